// Round 18
// baseline (465.518 us; speedup 1.0000x reference)
//
#include <hip/hip_runtime.h>
#include <hip/hip_bf16.h>
#include <stdint.h>

typedef __attribute__((ext_vector_type(8))) short bf16x8;
typedef __attribute__((ext_vector_type(4))) short short4v;
typedef __attribute__((ext_vector_type(4))) float f32x4;

#define GLOAD16(g, s) __builtin_amdgcn_global_load_lds( \
    (const __attribute__((address_space(1))) void*)(g),  \
    (__attribute__((address_space(3))) void*)(s), 16, 0, 0)

static __device__ __forceinline__ short f2bf(float f) {
  unsigned u = __builtin_bit_cast(unsigned, f);
  u += 0x7fffu + ((u >> 16) & 1u);
  return (short)(u >> 16);
}

static __device__ __forceinline__ f32x4 mfma16(bf16x8 a, bf16x8 b, f32x4 c) {
  return __builtin_amdgcn_mfma_f32_16x16x32_bf16(a, b, c, 0, 0, 0);
}

// ---------------- prep_all: weight converts + LN1 in ONE dispatch ----------
__global__ __launch_bounds__(256) void prep_all(
    const float* __restrict__ WQ, const float* __restrict__ WK,
    const float* __restrict__ WV, const float* __restrict__ WO,
    const float* __restrict__ w1, const float* __restrict__ w2,
    const float* __restrict__ x, const float* __restrict__ lnw,
    const float* __restrict__ lnb,
    short* __restrict__ Wqkv, short* __restrict__ Wob,
    short* __restrict__ w1b, short* __restrict__ w2b,
    short* __restrict__ yb) {
  __shared__ float red[8];
  const int bi = blockIdx.x, tid = threadIdx.x;
  if (bi < 3072) {
    const float* src = bi < 1024 ? WQ : (bi < 2048 ? WK : WV);
    const float4 v = ((const float4*)(src + (size_t)(bi & 1023) * 1024))[tid];
    short4v o;
    o[0] = f2bf(v.x); o[1] = f2bf(v.y); o[2] = f2bf(v.z); o[3] = f2bf(v.w);
    ((short4v*)(Wqkv + (size_t)bi * 1024))[tid] = o;
  } else if (bi < 7168) {
    const int i = (bi - 3072) * 256 + tid;
    const float4 v = ((const float4*)w1)[i];
    short4v o;
    o[0] = f2bf(v.x); o[1] = f2bf(v.y); o[2] = f2bf(v.z); o[3] = f2bf(v.w);
    ((short4v*)w1b)[i] = o;
  } else if (bi < 11264) {
    const int i = (bi - 7168) * 256 + tid;
    const float4 v = ((const float4*)w2)[i];
    short4v o;
    o[0] = f2bf(v.x); o[1] = f2bf(v.y); o[2] = f2bf(v.z); o[3] = f2bf(v.w);
    ((short4v*)w2b)[i] = o;
  } else if (bi < 15360) {
    const int idx = (bi - 11264) * 256 + tid;  // [D][H*DH] out
    const int d = idx >> 10, cc = idx & 1023;
    const int i = cc >> 6, h = cc & 63;
    Wob[idx] = f2bf(WO[((size_t)d * 64 + h) * 16 + i]);
  } else {
    const int row = bi - 15360;
    const int lane = tid & 63, wave = tid >> 6;
    const float4 xv = *(const float4*)&x[(size_t)row * 1024 + tid * 4];
    float s1 = xv.x + xv.y + xv.z + xv.w;
    float s2 = xv.x * xv.x + xv.y * xv.y + xv.z * xv.z + xv.w * xv.w;
#pragma unroll
    for (int off = 1; off < 64; off <<= 1) {
      s1 += __shfl_xor(s1, off);
      s2 += __shfl_xor(s2, off);
    }
    if (lane == 0) { red[wave] = s1; red[4 + wave] = s2; }
    __syncthreads();
    s1 = red[0] + red[1] + red[2] + red[3];
    s2 = red[4] + red[5] + red[6] + red[7];
    const float mu = s1 * (1.0f / 1024.0f);
    const float var = s2 * (1.0f / 1024.0f) - mu * mu;
    const float rs = rsqrtf(var + 1e-5f);
    const float4 wv = *(const float4*)&lnw[tid * 4];
    const float4 bv = *(const float4*)&lnb[tid * 4];
    short4v o;
    o[0] = f2bf((xv.x - mu) * rs * wv.x + bv.x);
    o[1] = f2bf((xv.y - mu) * rs * wv.y + bv.y);
    o[2] = f2bf((xv.z - mu) * rs * wv.z + bv.z);
    o[3] = f2bf((xv.w - mu) * rs * wv.w + bv.w);
    *(short4v*)&yb[(size_t)row * 1024 + tid * 4] = o;
  }
}

// ---------------- LayerNorm standalone (LN2) ----------------
__global__ __launch_bounds__(256) void ln_kernel(const float* __restrict__ x,
                                                 const float* __restrict__ w,
                                                 const float* __restrict__ b,
                                                 short* __restrict__ y) {
  const int row = blockIdx.x, tid = threadIdx.x;
  const int lane = tid & 63, wave = tid >> 6;
  const float4 xv = *(const float4*)&x[(size_t)row * 1024 + tid * 4];
  float s1 = xv.x + xv.y + xv.z + xv.w;
  float s2 = xv.x * xv.x + xv.y * xv.y + xv.z * xv.z + xv.w * xv.w;
#pragma unroll
  for (int off = 1; off < 64; off <<= 1) {
    s1 += __shfl_xor(s1, off);
    s2 += __shfl_xor(s2, off);
  }
  __shared__ float red[8];
  if (lane == 0) { red[wave] = s1; red[4 + wave] = s2; }
  __syncthreads();
  s1 = red[0] + red[1] + red[2] + red[3];
  s2 = red[4] + red[5] + red[6] + red[7];
  const float mu = s1 * (1.0f / 1024.0f);
  const float var = s2 * (1.0f / 1024.0f) - mu * mu;
  const float rs = rsqrtf(var + 1e-5f);
  const float4 wv = *(const float4*)&w[tid * 4];
  const float4 bv = *(const float4*)&b[tid * 4];
  short4v o;
  o[0] = f2bf((xv.x - mu) * rs * wv.x + bv.x);
  o[1] = f2bf((xv.y - mu) * rs * wv.y + bv.y);
  o[2] = f2bf((xv.z - mu) * rs * wv.z + bv.z);
  o[3] = f2bf((xv.w - mu) * rs * wv.w + bv.w);
  *(short4v*)&y[(size_t)row * 1024 + tid * 4] = o;
}

// ------- GEMM: C = A*Bw^T, bf16, fp32 acc, tile BMxBN -----
// All GEMMs now 128x64 DBUF (48KB LDS -> 3 blocks/CU): stage(t+1) issued
// before compute(t), single bottom barrier. Proven on WO/MLP2 (R17 -14us);
// extended to QKV/MLP1 this round. B-fetch amplification absorbed by L2/L3
// (working set ~30MB << 256MB; XCD-chunked remap keeps panel-sharing blocks
// on one XCD's L2).
template <int MODE, int BM, int BN, bool DBUF>
__global__ __launch_bounds__(256) void gemm_bf16k(
    const short* __restrict__ A, const short* __restrict__ Bw,
    float* __restrict__ outF, short* __restrict__ outB,
    const float* __restrict__ resid, const float* __restrict__ bias,
    int M, int N, int K) {
  constexpr int RBM = BM / 2, RBN = BN / 2;
  constexpr int FM = RBM / 16, FN = RBN / 16;
  constexpr int TCA = BM / 8, TCB = BN / 8, TC = TCA + TCB;
  constexpr int NB = DBUF ? 2 : 1;
  __shared__ short As[NB][BM * 64];
  __shared__ short Bs[NB][BN * 64];
  const int tid = threadIdx.x, lane = tid & 63, wave = tid >> 6;
  const int nbx = gridDim.x, nwg = nbx * gridDim.y;
  int lid = (int)blockIdx.y * nbx + (int)blockIdx.x;
  lid = (lid & 7) * (nwg >> 3) + (lid >> 3);   // xcd-chunked remap (nwg%8==0)
  const int m0 = (lid / nbx) * BM, n0 = (lid % nbx) * BN;
  const int wm = (wave & 1) * RBM, wn = (wave >> 1) * RBN;
  const int lr = lane >> 3;        // row within 8-row chunk
  const int lc = (lane & 7) * 8;   // elem col within chunk row
  f32x4 acc[FM][FN] = {};

  auto stage = [&](int d, int kt) {
#pragma unroll
    for (int i = 0; i < TC / 4; ++i) {
      const int ch = i * 4 + wave;
      if (ch < TCA) {
        GLOAD16(A + (size_t)(m0 + ch * 8 + lr) * K + kt + lc, &As[d][ch * 512]);
      } else {
        const int cb = ch - TCA;
        GLOAD16(Bw + (size_t)(n0 + cb * 8 + lr) * K + kt + lc, &Bs[d][cb * 512]);
      }
    }
  };
  auto compute = [&](int d) {
#pragma unroll
    for (int kk = 0; kk < 64; kk += 32) {
      bf16x8 af[FM], bfr[FN];
#pragma unroll
      for (int i2 = 0; i2 < FM; ++i2)
        af[i2] = *(const bf16x8*)&As[d][(wm + i2 * 16 + (lane & 15)) * 64 + kk + (lane >> 4) * 8];
#pragma unroll
      for (int j2 = 0; j2 < FN; ++j2)
        bfr[j2] = *(const bf16x8*)&Bs[d][(wn + j2 * 16 + (lane & 15)) * 64 + kk + (lane >> 4) * 8];
#pragma unroll
      for (int i2 = 0; i2 < FM; ++i2)
#pragma unroll
        for (int j2 = 0; j2 < FN; ++j2)
          acc[i2][j2] = mfma16(af[i2], bfr[j2], acc[i2][j2]);
    }
  };

  const int nt = K >> 6;
  if constexpr (DBUF) {
    stage(0, 0);
    __syncthreads();
    for (int t = 0; t < nt; ++t) {
      const int cur = t & 1;
      if (t + 1 < nt) stage(cur ^ 1, (t + 1) << 6);
      compute(cur);
      __syncthreads();
    }
  } else {
    for (int t = 0; t < nt; ++t) {
      stage(0, t << 6);
      __syncthreads();
      compute(0);
      __syncthreads();
    }
  }

#pragma unroll
  for (int i2 = 0; i2 < FM; ++i2)
#pragma unroll
    for (int j2 = 0; j2 < FN; ++j2)
#pragma unroll
      for (int r = 0; r < 4; ++r) {
        const int m = m0 + wm + i2 * 16 + (lane >> 4) * 4 + r;
        const int n = n0 + wn + j2 * 16 + (lane & 15);
        const float v = acc[i2][j2][r];
        if (MODE == 0) {
          const size_t oi = (size_t)(n >> 10) * 4194304 +
              ((size_t)((m >> 11) * 16 + ((n & 1023) >> 6)) * 2048 + (m & 2047)) * 64 +
              (n & 63);
          outB[oi] = f2bf(v);
        } else if (MODE == 1) {
          outF[(size_t)m * N + n] = resid[(size_t)m * N + n] + v;
        } else if (MODE == 2) {
          const float t2 = v + bias[n];
          outB[(size_t)m * N + n] = f2bf(t2 > 0.0f ? t2 : 0.0f);
        } else {
          outF[(size_t)m * N + n] = resid[(size_t)m * N + n] + v + bias[n];
        }
      }
}

// ---------------- V transpose: [BH][S][64] -> [BH][64][S] ----------------
__global__ __launch_bounds__(256) void transpose_v(const short* __restrict__ V,
                                                   short* __restrict__ Vt) {
  __shared__ short t[64][72];
  const int bi = blockIdx.y;
  const int p0 = blockIdx.x * 64;
  const short* Vh = V + (size_t)bi * 2048 * 64;
  short* Vth = Vt + (size_t)bi * 64 * 2048;
  const int tid = threadIdx.x;
  {
    const int pr = tid >> 2, h0 = (tid & 3) * 16;
    const bf16x8* src = (const bf16x8*)&Vh[(size_t)(p0 + pr) * 64 + h0];
    bf16x8 v0 = src[0], v1 = src[1];
#pragma unroll
    for (int j = 0; j < 8; ++j) { t[pr][h0 + j] = v0[j]; t[pr][h0 + 8 + j] = v1[j]; }
  }
  __syncthreads();
  {
    const int hr = tid >> 2, pq = (tid & 3) * 16;
    bf16x8 o0, o1;
#pragma unroll
    for (int j = 0; j < 8; ++j) { o0[j] = t[pq + j][hr]; o1[j] = t[pq + 8 + j][hr]; }
    *(bf16x8*)&Vth[(size_t)hr * 2048 + p0 + pq] = o0;
    *(bf16x8*)&Vth[(size_t)hr * 2048 + p0 + pq + 8] = o1;
  }
}

// ---- attn_flash v4 + T5 setprio (R16/R17 best-measured, unchanged) ----
__global__ __launch_bounds__(256, 2) void attn_flash(
    const short* __restrict__ Q, const short* __restrict__ K,
    const short* __restrict__ Vt, float* __restrict__ ml,
    short* __restrict__ zb) {
  __shared__ __align__(16) char smem[34816];
  const int tid = threadIdx.x, lane = tid & 63, pc = tid >> 6;
  const int g = lane >> 4, c = lane & 15;
  const int qt = 63 - (int)blockIdx.x;   // heavy q-tiles dispatch first
  const int bi = blockIdx.y;
  const int b = bi >> 4, hd = bi & 15;
  const size_t hoff = (size_t)bi * 2048 * 64;
  const short* Qh = Q + hoff;
  const short* Kh = K + hoff;
  const short* Vth = Vt + hoff;
  short* zbh = zb + (size_t)b * 2048 * 1024 + hd * 64;

  const int qw = qt * 32;
  const int P = qw + 32;
  const int csz = ((P + 511) >> 9) << 7;   // ceil(P/4) rounded up to 128
  const int p_lo = pc * csz;
  const int p_hi = min(p_lo + csz, P);

  short* pbuf = (short*)smem + pc * 4224;  // 32 rows x pitch 132
  float* mlb  = (float*)(smem + 33792);
  float* zm   = (float*)smem;

  const bf16x8* qp0 = (const bf16x8*)&Qh[(size_t)(qw + c) * 64];
  const bf16x8* qp1 = (const bf16x8*)&Qh[(size_t)(qw + 16 + c) * 64];
  bf16x8 aq[2][2];
  aq[0][0] = qp0[g]; aq[0][1] = qp0[4 + g];
  aq[1][0] = qp1[g]; aq[1][1] = qp1[4 + g];

  float m4[2][4], l4[2][4];
  f32x4 zacc[2][4] = {};
#pragma unroll
  for (int rb = 0; rb < 2; ++rb)
#pragma unroll
    for (int r = 0; r < 4; ++r) { m4[rb][r] = -1e30f; l4[rb][r] = 0.0f; }

  for (int p0 = p_lo; p0 < p_hi; p0 += 128) {
    bf16x8 k0[8], k1[8];
#pragma unroll
    for (int kb = 0; kb < 8; ++kb) {
      int row = p0 + kb * 16 + c;
      row = row < 2047 ? row : 2047;   // clamp; masked below via p<=q
      const bf16x8* kp = (const bf16x8*)&Kh[(size_t)row * 64];
      k0[kb] = kp[g]; k1[kb] = kp[4 + g];
    }
    const bool needmask = (p0 + 128 > qw);   // wave-uniform
#pragma unroll
    for (int rb = 0; rb < 2; ++rb) {
      f32x4 s[8];
      __builtin_amdgcn_s_setprio(1);
#pragma unroll
      for (int kb = 0; kb < 8; ++kb) {
        f32x4 z4 = {0.0f, 0.0f, 0.0f, 0.0f};
        z4 = mfma16(aq[rb][0], k0[kb], z4);
        s[kb] = mfma16(aq[rb][1], k1[kb], z4);
      }
      __builtin_amdgcn_s_setprio(0);
#pragma unroll
      for (int r = 0; r < 4; ++r) {
        const int q = qw + rb * 16 + g * 4 + r;
        float v[8];
        if (needmask) {
#pragma unroll
          for (int kb = 0; kb < 8; ++kb)
            v[kb] = (p0 + kb * 16 + c <= q) ? s[kb][r] * 0.125f : -1e30f;
        } else {
#pragma unroll
          for (int kb = 0; kb < 8; ++kb) v[kb] = s[kb][r] * 0.125f;
        }
        float mx = fmaxf(fmaxf(fmaxf(v[0], v[1]), fmaxf(v[2], v[3])),
                         fmaxf(fmaxf(v[4], v[5]), fmaxf(v[6], v[7])));
#pragma unroll
        for (int off = 1; off < 16; off <<= 1)
          mx = fmaxf(mx, __shfl_xor(mx, off));   // row-uniform across c-lanes
        const float mn = fmaxf(m4[rb][r], mx);
        const float fac = __expf(m4[rb][r] - mn);
        m4[rb][r] = mn;
        float lsum = 0.0f;
        if (needmask) {
#pragma unroll
          for (int kb = 0; kb < 8; ++kb) {
            const int p = p0 + kb * 16 + c;
            const float e = (p <= q) ? __expf(v[kb] - mn) : 0.0f;
            lsum += e;
            pbuf[(rb * 16 + g * 4 + r) * 132 + kb * 16 + c] = f2bf(e);
          }
        } else {
#pragma unroll
          for (int kb = 0; kb < 8; ++kb) {
            const float e = __expf(v[kb] - mn);
            lsum += e;
            pbuf[(rb * 16 + g * 4 + r) * 132 + kb * 16 + c] = f2bf(e);
          }
        }
        l4[rb][r] = l4[rb][r] * fac + lsum;
#pragma unroll
        for (int hb = 0; hb < 4; ++hb) zacc[rb][hb][r] *= fac;
      }
    }
    // PV: pa from pbuf (two 8B reads, 8B-aligned at pitch 132), bv from Vt
    __builtin_amdgcn_s_setprio(1);
#pragma unroll
    for (int j = 0; j < 4; ++j) {
      const short4v p0lo = *(const short4v*)&pbuf[c * 132 + j * 32 + g * 8];
      const short4v p0hi = *(const short4v*)&pbuf[c * 132 + j * 32 + g * 8 + 4];
      const short4v p1lo = *(const short4v*)&pbuf[(16 + c) * 132 + j * 32 + g * 8];
      const short4v p1hi = *(const short4v*)&pbuf[(16 + c) * 132 + j * 32 + g * 8 + 4];
      const bf16x8 pa0 = __builtin_shufflevector(p0lo, p0hi, 0, 1, 2, 3, 4, 5, 6, 7);
      const bf16x8 pa1 = __builtin_shufflevector(p1lo, p1hi, 0, 1, 2, 3, 4, 5, 6, 7);
#pragma unroll
      for (int hb = 0; hb < 4; ++hb) {
        const bf16x8 bv =
            *(const bf16x8*)&Vth[(size_t)(hb * 16 + c) * 2048 + p0 + j * 32 + g * 8];
        zacc[0][hb] = mfma16(pa0, bv, zacc[0][hb]);
        zacc[1][hb] = mfma16(pa1, bv, zacc[1][hb]);
      }
    }
    __builtin_amdgcn_s_setprio(0);
  }

  // cross-lane l sum (m already row-uniform)
#pragma unroll
  for (int rb = 0; rb < 2; ++rb)
#pragma unroll
    for (int r = 0; r < 4; ++r)
#pragma unroll
      for (int off = 1; off < 16; off <<= 1)
        l4[rb][r] += __shfl_xor(l4[rb][r], off);

  if (c == 0) {
#pragma unroll
    for (int rb = 0; rb < 2; ++rb)
#pragma unroll
      for (int r = 0; r < 4; ++r) {
        mlb[(pc * 32 + rb * 16 + g * 4 + r) * 2 + 0] = m4[rb][r];
        mlb[(pc * 32 + rb * 16 + g * 4 + r) * 2 + 1] = l4[rb][r];
      }
  }
  __syncthreads();  // pbuf dead in all waves; mlb visible

  // phase C: m-aware flash combine of the 4 chunk partials
  if (pc != 0) {
#pragma unroll
    for (int rb = 0; rb < 2; ++rb)
#pragma unroll
      for (int hb = 0; hb < 4; ++hb)
#pragma unroll
        for (int r = 0; r < 4; ++r)
          zm[((pc - 1) * 32 + rb * 16 + g * 4 + r) * 68 + hb * 16 + c] = zacc[rb][hb][r];
  }
  __syncthreads();
  if (pc == 0) {
#pragma unroll
    for (int rb = 0; rb < 2; ++rb)
#pragma unroll
      for (int r = 0; r < 4; ++r) {
        const int row = rb * 16 + g * 4 + r;
        float M = -1e30f;
#pragma unroll
        for (int j = 0; j < 4; ++j) M = fmaxf(M, mlb[(j * 32 + row) * 2 + 0]);
        float w[4], L = 0.0f;
#pragma unroll
        for (int j = 0; j < 4; ++j) {
          w[j] = __expf(mlb[(j * 32 + row) * 2 + 0] - M);
          L += mlb[(j * 32 + row) * 2 + 1] * w[j];
        }
        const float iL = 1.0f / L;
#pragma unroll
        for (int hb = 0; hb < 4; ++hb) {
          float z = zacc[rb][hb][r] * w[0];
#pragma unroll
          for (int j = 1; j < 4; ++j)
            z += zm[((j - 1) * 32 + row) * 68 + hb * 16 + c] * w[j];
          zbh[(size_t)(qw + row) * 1024 + hb * 16 + c] = f2bf(z * iL);
        }
        if (c == 0)
          ((float2*)ml)[(size_t)bi * 2048 + qw + row] = make_float2(M, iL);
      }
  }
}

// ---------------- att_write: materialize att, massively parallel -----------
__global__ __launch_bounds__(256) void att_write(
    const short* __restrict__ Q, const short* __restrict__ K,
    const float* __restrict__ ml, float* __restrict__ att) {
  __shared__ float fbuf_s[4][16 * 36];
  const int tid = threadIdx.x, lane = tid & 63, wave = tid >> 6;
  const int g = lane >> 4, c = lane & 15;
  const int qt = blockIdx.x, pt = blockIdx.y, bi = blockIdx.z;
  const int qs = wave >> 1, ph = wave & 1;
  const int qw = qt * 32 + qs * 16;
  const int pb = pt * 256 + ph * 128;
  float* atth = att + (size_t)bi * 2048 * 2048;
  const int r0 = lane >> 3, c4 = (lane & 7) * 4;

  if (pb > qw + 15) {  // strip entirely above the diagonal: pure zeros
    const f32x4 zf = {0.0f, 0.0f, 0.0f, 0.0f};
#pragma unroll
    for (int j = 0; j < 4; ++j) {
      __builtin_nontemporal_store(zf, (f32x4*)&atth[(size_t)(qw + r0) * 2048 + pb + j * 32 + c4]);
      __builtin_nontemporal_store(zf, (f32x4*)&atth[(size_t)(qw + 8 + r0) * 2048 + pb + j * 32 + c4]);
    }
    return;
  }

  const size_t hoff = (size_t)bi * 2048 * 64;
  const short* Qh = Q + hoff;
  const short* Kh = K + hoff;
  const bf16x8* qp = (const bf16x8*)&Qh[(size_t)(qw + c) * 64];
  const bf16x8 aq0 = qp[g], aq1 = qp[4 + g];
  float m4[4], il[4];
#pragma unroll
  for (int r = 0; r < 4; ++r) {
    const float2 t = ((const float2*)ml)[(size_t)bi * 2048 + qw + g * 4 + r];
    m4[r] = t.x; il[r] = t.y;
  }
  float* fbuf = fbuf_s[wave];
  for (int p0 = pb; p0 < pb + 128; p0 += 32) {
    const bf16x8* kp0 = (const bf16x8*)&Kh[(size_t)(p0 + c) * 64];
    const bf16x8* kp1 = (const bf16x8*)&Kh[(size_t)(p0 + 16 + c) * 64];
    f32x4 s0 = {0.0f, 0.0f, 0.0f, 0.0f}, s1 = {0.0f, 0.0f, 0.0f, 0.0f};
    s0 = mfma16(aq0, kp0[g], s0);
    s0 = mfma16(aq1, kp0[4 + g], s0);
    s1 = mfma16(aq0, kp1[g], s1);
    s1 = mfma16(aq1, kp1[4 + g], s1);
#pragma unroll
    for (int f = 0; f < 2; ++f) {
      const f32x4& ss = f ? s1 : s0;
#pragma unroll
      for (int r = 0; r < 4; ++r) {
        const int q = qw + g * 4 + r, p = p0 + f * 16 + c;
        const float e = (p <= q) ? __expf(ss[r] * 0.125f - m4[r]) * il[r] : 0.0f;
        fbuf[(g * 4 + r) * 36 + f * 16 + c] = e;
      }
    }
    const f32x4 v0 = *(const f32x4*)&fbuf[r0 * 36 + c4];
    const f32x4 v1 = *(const f32x4*)&fbuf[(8 + r0) * 36 + c4];
    __builtin_nontemporal_store(v0, (f32x4*)&atth[(size_t)(qw + r0) * 2048 + p0 + c4]);
    __builtin_nontemporal_store(v1, (f32x4*)&atth[(size_t)(qw + 8 + r0) * 2048 + p0 + c4]);
  }
}

// ---------------- launch ----------------
extern "C" void kernel_launch(void* const* d_in, const int* in_sizes, int n_in,
                              void* d_out, int out_size, void* d_ws, size_t ws_size,
                              hipStream_t stream) {
  (void)in_sizes; (void)n_in; (void)out_size; (void)ws_size;
  const float* x    = (const float*)d_in[0];
  const float* WQ   = (const float*)d_in[1];
  const float* WK   = (const float*)d_in[2];
  const float* WV   = (const float*)d_in[3];
  const float* WO   = (const float*)d_in[4];
  const float* lnaw = (const float*)d_in[5];
  const float* lnab = (const float*)d_in[6];
  const float* lnmw = (const float*)d_in[7];
  const float* lnmb = (const float*)d_in[8];
  const float* w1   = (const float*)d_in[9];
  const float* b1   = (const float*)d_in[10];
  const float* w2   = (const float*)d_in[11];
  const float* b2   = (const float*)d_in[12];

  char* ws = (char*)d_ws;
  const size_t MB = 1024 * 1024;
  short* Wqkv = (short*)(ws + 0 * MB);   // 6MB: packed [3072][1024] bf16
  short* Wob  = (short*)(ws + 6 * MB);   // 2MB
  short* w1b  = (short*)(ws + 8 * MB);   // 8MB
  short* w2b  = (short*)(ws + 16 * MB);  // 8MB
  short* yb   = (short*)(ws + 24 * MB);  // 8MB (LN1 out; reused for LN2 out)
  short* Qb   = (short*)(ws + 32 * MB);  // 8MB  } contiguous: fused QKV
  short* Kb   = (short*)(ws + 40 * MB);  // 8MB  } scatter writes sel*4M
  short* Vb   = (short*)(ws + 48 * MB);  // 8MB  }
  short* Vtb  = (short*)(ws + 56 * MB);  // 8MB
  short* zbuf = (short*)(ws + 64 * MB);  // 8MB
  float* x1   = (float*)(ws + 72 * MB);  // 16MB (written after att_write reads mlw)
  float* mlw  = (float*)(ws + 72 * MB);  // 512KB, overlaps x1 (stream-ordered:
                                         // att_write consumes mlw BEFORE gemm1
                                         // writes x1)
  short* hb   = (short*)(ws + 32 * MB);  // 32MB, reuses Q/K/V/Vt (dead by MLP1)

  float* outx = (float*)d_out;
  float* att  = outx + (size_t)2 * 2048 * 1024;  // output 1 region

  // weight converts + LN1 in one dispatch
  prep_all<<<dim3(19456), dim3(256), 0, stream>>>(
      WQ, WK, WV, WO, w1, w2, x, lnaw, lnab, Wqkv, Wob, w1b, w2b, yb);

  // fused QKV projection: 128x64 DBUF, 1536 blocks (3/CU)
  gemm_bf16k<0, 128, 64, true><<<dim3(48, 32), dim3(256), 0, stream>>>(
      yb, Wqkv, nullptr, Qb, nullptr, nullptr, 4096, 3072, 1024);

  // V transpose for PV B-operand
  transpose_v<<<dim3(32, 32), dim3(256), 0, stream>>>(Vb, Vtb);

  // attention stats + z (single-pass online flash + setprio)
  attn_flash<<<dim3(64, 32), dim3(256), 0, stream>>>(Qb, Kb, Vtb, mlw, zbuf);

  // att materialization (embarrassingly parallel, store-BW-bound)
  att_write<<<dim3(64, 8, 32), dim3(256), 0, stream>>>(Qb, Kb, mlw, att);

  // output projection + residual -> x1; 128x64 DBUF
  gemm_bf16k<1, 128, 64, true><<<dim3(16, 32), dim3(256), 0, stream>>>(
      zbuf, Wob, x1, nullptr, x, nullptr, 4096, 1024, 1024);

  // LN2
  ln_kernel<<<dim3(4096), dim3(256), 0, stream>>>(x1, lnmw, lnmb, yb);

  // MLP1: 128x64 DBUF, 2048 blocks (3/CU)
  gemm_bf16k<2, 128, 64, true><<<dim3(64, 32), dim3(256), 0, stream>>>(
      yb, w1b, nullptr, hb, nullptr, b1, 4096, 4096, 1024);
  // MLP2: 128x64 DBUF
  gemm_bf16k<3, 128, 64, true><<<dim3(16, 32), dim3(256), 0, stream>>>(
      hb, w2b, outx, nullptr, x1, b2, 4096, 1024, 4096);
}

// Round 19
// 451.290 us; speedup vs baseline: 1.0315x; 1.0315x over previous
//
#include <hip/hip_runtime.h>
#include <hip/hip_bf16.h>
#include <stdint.h>

typedef __attribute__((ext_vector_type(8))) short bf16x8;
typedef __attribute__((ext_vector_type(4))) short short4v;
typedef __attribute__((ext_vector_type(4))) float f32x4;

#define GLOAD16(g, s) __builtin_amdgcn_global_load_lds( \
    (const __attribute__((address_space(1))) void*)(g),  \
    (__attribute__((address_space(3))) void*)(s), 16, 0, 0)

static __device__ __forceinline__ short f2bf(float f) {
  unsigned u = __builtin_bit_cast(unsigned, f);
  u += 0x7fffu + ((u >> 16) & 1u);
  return (short)(u >> 16);
}

static __device__ __forceinline__ f32x4 mfma16(bf16x8 a, bf16x8 b, f32x4 c) {
  return __builtin_amdgcn_mfma_f32_16x16x32_bf16(a, b, c, 0, 0, 0);
}

// ---------------- prep_all: weight converts + LN1 in ONE dispatch ----------
__global__ __launch_bounds__(256) void prep_all(
    const float* __restrict__ WQ, const float* __restrict__ WK,
    const float* __restrict__ WV, const float* __restrict__ WO,
    const float* __restrict__ w1, const float* __restrict__ w2,
    const float* __restrict__ x, const float* __restrict__ lnw,
    const float* __restrict__ lnb,
    short* __restrict__ Wqkv, short* __restrict__ Wob,
    short* __restrict__ w1b, short* __restrict__ w2b,
    short* __restrict__ yb) {
  __shared__ float red[8];
  const int bi = blockIdx.x, tid = threadIdx.x;
  if (bi < 3072) {
    const float* src = bi < 1024 ? WQ : (bi < 2048 ? WK : WV);
    const float4 v = ((const float4*)(src + (size_t)(bi & 1023) * 1024))[tid];
    short4v o;
    o[0] = f2bf(v.x); o[1] = f2bf(v.y); o[2] = f2bf(v.z); o[3] = f2bf(v.w);
    ((short4v*)(Wqkv + (size_t)bi * 1024))[tid] = o;
  } else if (bi < 7168) {
    const int i = (bi - 3072) * 256 + tid;
    const float4 v = ((const float4*)w1)[i];
    short4v o;
    o[0] = f2bf(v.x); o[1] = f2bf(v.y); o[2] = f2bf(v.z); o[3] = f2bf(v.w);
    ((short4v*)w1b)[i] = o;
  } else if (bi < 11264) {
    const int i = (bi - 7168) * 256 + tid;
    const float4 v = ((const float4*)w2)[i];
    short4v o;
    o[0] = f2bf(v.x); o[1] = f2bf(v.y); o[2] = f2bf(v.z); o[3] = f2bf(v.w);
    ((short4v*)w2b)[i] = o;
  } else if (bi < 15360) {
    const int idx = (bi - 11264) * 256 + tid;  // [D][H*DH] out
    const int d = idx >> 10, cc = idx & 1023;
    const int i = cc >> 6, h = cc & 63;
    Wob[idx] = f2bf(WO[((size_t)d * 64 + h) * 16 + i]);
  } else {
    const int row = bi - 15360;
    const int lane = tid & 63, wave = tid >> 6;
    const float4 xv = *(const float4*)&x[(size_t)row * 1024 + tid * 4];
    float s1 = xv.x + xv.y + xv.z + xv.w;
    float s2 = xv.x * xv.x + xv.y * xv.y + xv.z * xv.z + xv.w * xv.w;
#pragma unroll
    for (int off = 1; off < 64; off <<= 1) {
      s1 += __shfl_xor(s1, off);
      s2 += __shfl_xor(s2, off);
    }
    if (lane == 0) { red[wave] = s1; red[4 + wave] = s2; }
    __syncthreads();
    s1 = red[0] + red[1] + red[2] + red[3];
    s2 = red[4] + red[5] + red[6] + red[7];
    const float mu = s1 * (1.0f / 1024.0f);
    const float var = s2 * (1.0f / 1024.0f) - mu * mu;
    const float rs = rsqrtf(var + 1e-5f);
    const float4 wv = *(const float4*)&lnw[tid * 4];
    const float4 bv = *(const float4*)&lnb[tid * 4];
    short4v o;
    o[0] = f2bf((xv.x - mu) * rs * wv.x + bv.x);
    o[1] = f2bf((xv.y - mu) * rs * wv.y + bv.y);
    o[2] = f2bf((xv.z - mu) * rs * wv.z + bv.z);
    o[3] = f2bf((xv.w - mu) * rs * wv.w + bv.w);
    *(short4v*)&yb[(size_t)row * 1024 + tid * 4] = o;
  }
}

// ---------------- LayerNorm standalone (LN2) ----------------
__global__ __launch_bounds__(256) void ln_kernel(const float* __restrict__ x,
                                                 const float* __restrict__ w,
                                                 const float* __restrict__ b,
                                                 short* __restrict__ y) {
  const int row = blockIdx.x, tid = threadIdx.x;
  const int lane = tid & 63, wave = tid >> 6;
  const float4 xv = *(const float4*)&x[(size_t)row * 1024 + tid * 4];
  float s1 = xv.x + xv.y + xv.z + xv.w;
  float s2 = xv.x * xv.x + xv.y * xv.y + xv.z * xv.z + xv.w * xv.w;
#pragma unroll
  for (int off = 1; off < 64; off <<= 1) {
    s1 += __shfl_xor(s1, off);
    s2 += __shfl_xor(s2, off);
  }
  __shared__ float red[8];
  if (lane == 0) { red[wave] = s1; red[4 + wave] = s2; }
  __syncthreads();
  s1 = red[0] + red[1] + red[2] + red[3];
  s2 = red[4] + red[5] + red[6] + red[7];
  const float mu = s1 * (1.0f / 1024.0f);
  const float var = s2 * (1.0f / 1024.0f) - mu * mu;
  const float rs = rsqrtf(var + 1e-5f);
  const float4 wv = *(const float4*)&w[tid * 4];
  const float4 bv = *(const float4*)&b[tid * 4];
  short4v o;
  o[0] = f2bf((xv.x - mu) * rs * wv.x + bv.x);
  o[1] = f2bf((xv.y - mu) * rs * wv.y + bv.y);
  o[2] = f2bf((xv.z - mu) * rs * wv.z + bv.z);
  o[3] = f2bf((xv.w - mu) * rs * wv.w + bv.w);
  *(short4v*)&y[(size_t)row * 1024 + tid * 4] = o;
}

// ------- GEMM: C = A*Bw^T, bf16, fp32 acc, tile BMxBN -----
// Shape-conditional config (R17/R18 measured):
//   Large-N GEMMs (QKV N=3072, MLP1 N=4096): 128x128 single-buffer — higher
//     arithmetic intensity per staged byte; halving BN doubled A-panel reader
//     count and regressed (R18 +14us).
//   N=1024 GEMMs (WO-proj, MLP2): 128x64 DBUF (48KB -> 3 blocks/CU) — thin
//     TLP can't hide the per-K-step drain; dbuf fixed it (R17 -14us).
template <int MODE, int BM, int BN, bool DBUF>
__global__ __launch_bounds__(256) void gemm_bf16k(
    const short* __restrict__ A, const short* __restrict__ Bw,
    float* __restrict__ outF, short* __restrict__ outB,
    const float* __restrict__ resid, const float* __restrict__ bias,
    int M, int N, int K) {
  constexpr int RBM = BM / 2, RBN = BN / 2;
  constexpr int FM = RBM / 16, FN = RBN / 16;
  constexpr int TCA = BM / 8, TCB = BN / 8, TC = TCA + TCB;
  constexpr int NB = DBUF ? 2 : 1;
  __shared__ short As[NB][BM * 64];
  __shared__ short Bs[NB][BN * 64];
  const int tid = threadIdx.x, lane = tid & 63, wave = tid >> 6;
  const int nbx = gridDim.x, nwg = nbx * gridDim.y;
  int lid = (int)blockIdx.y * nbx + (int)blockIdx.x;
  lid = (lid & 7) * (nwg >> 3) + (lid >> 3);   // xcd-chunked remap (nwg%8==0)
  const int m0 = (lid / nbx) * BM, n0 = (lid % nbx) * BN;
  const int wm = (wave & 1) * RBM, wn = (wave >> 1) * RBN;
  const int lr = lane >> 3;        // row within 8-row chunk
  const int lc = (lane & 7) * 8;   // elem col within chunk row
  f32x4 acc[FM][FN] = {};

  auto stage = [&](int d, int kt) {
#pragma unroll
    for (int i = 0; i < TC / 4; ++i) {
      const int ch = i * 4 + wave;
      if (ch < TCA) {
        GLOAD16(A + (size_t)(m0 + ch * 8 + lr) * K + kt + lc, &As[d][ch * 512]);
      } else {
        const int cb = ch - TCA;
        GLOAD16(Bw + (size_t)(n0 + cb * 8 + lr) * K + kt + lc, &Bs[d][cb * 512]);
      }
    }
  };
  auto compute = [&](int d) {
#pragma unroll
    for (int kk = 0; kk < 64; kk += 32) {
      bf16x8 af[FM], bfr[FN];
#pragma unroll
      for (int i2 = 0; i2 < FM; ++i2)
        af[i2] = *(const bf16x8*)&As[d][(wm + i2 * 16 + (lane & 15)) * 64 + kk + (lane >> 4) * 8];
#pragma unroll
      for (int j2 = 0; j2 < FN; ++j2)
        bfr[j2] = *(const bf16x8*)&Bs[d][(wn + j2 * 16 + (lane & 15)) * 64 + kk + (lane >> 4) * 8];
#pragma unroll
      for (int i2 = 0; i2 < FM; ++i2)
#pragma unroll
        for (int j2 = 0; j2 < FN; ++j2)
          acc[i2][j2] = mfma16(af[i2], bfr[j2], acc[i2][j2]);
    }
  };

  const int nt = K >> 6;
  if constexpr (DBUF) {
    stage(0, 0);
    __syncthreads();
    for (int t = 0; t < nt; ++t) {
      const int cur = t & 1;
      if (t + 1 < nt) stage(cur ^ 1, (t + 1) << 6);
      compute(cur);
      __syncthreads();
    }
  } else {
    for (int t = 0; t < nt; ++t) {
      stage(0, t << 6);
      __syncthreads();
      compute(0);
      __syncthreads();
    }
  }

#pragma unroll
  for (int i2 = 0; i2 < FM; ++i2)
#pragma unroll
    for (int j2 = 0; j2 < FN; ++j2)
#pragma unroll
      for (int r = 0; r < 4; ++r) {
        const int m = m0 + wm + i2 * 16 + (lane >> 4) * 4 + r;
        const int n = n0 + wn + j2 * 16 + (lane & 15);
        const float v = acc[i2][j2][r];
        if (MODE == 0) {
          const size_t oi = (size_t)(n >> 10) * 4194304 +
              ((size_t)((m >> 11) * 16 + ((n & 1023) >> 6)) * 2048 + (m & 2047)) * 64 +
              (n & 63);
          outB[oi] = f2bf(v);
        } else if (MODE == 1) {
          outF[(size_t)m * N + n] = resid[(size_t)m * N + n] + v;
        } else if (MODE == 2) {
          const float t2 = v + bias[n];
          outB[(size_t)m * N + n] = f2bf(t2 > 0.0f ? t2 : 0.0f);
        } else {
          outF[(size_t)m * N + n] = resid[(size_t)m * N + n] + v + bias[n];
        }
      }
}

// ---------------- V transpose: [BH][S][64] -> [BH][64][S] ----------------
__global__ __launch_bounds__(256) void transpose_v(const short* __restrict__ V,
                                                   short* __restrict__ Vt) {
  __shared__ short t[64][72];
  const int bi = blockIdx.y;
  const int p0 = blockIdx.x * 64;
  const short* Vh = V + (size_t)bi * 2048 * 64;
  short* Vth = Vt + (size_t)bi * 64 * 2048;
  const int tid = threadIdx.x;
  {
    const int pr = tid >> 2, h0 = (tid & 3) * 16;
    const bf16x8* src = (const bf16x8*)&Vh[(size_t)(p0 + pr) * 64 + h0];
    bf16x8 v0 = src[0], v1 = src[1];
#pragma unroll
    for (int j = 0; j < 8; ++j) { t[pr][h0 + j] = v0[j]; t[pr][h0 + 8 + j] = v1[j]; }
  }
  __syncthreads();
  {
    const int hr = tid >> 2, pq = (tid & 3) * 16;
    bf16x8 o0, o1;
#pragma unroll
    for (int j = 0; j < 8; ++j) { o0[j] = t[pq + j][hr]; o1[j] = t[pq + 8 + j][hr]; }
    *(bf16x8*)&Vth[(size_t)hr * 2048 + p0 + pq] = o0;
    *(bf16x8*)&Vth[(size_t)hr * 2048 + p0 + pq + 8] = o1;
  }
}

// ---- attn_flash v4 + T5 setprio (best-measured, unchanged) ----
__global__ __launch_bounds__(256, 2) void attn_flash(
    const short* __restrict__ Q, const short* __restrict__ K,
    const short* __restrict__ Vt, float* __restrict__ ml,
    short* __restrict__ zb) {
  __shared__ __align__(16) char smem[34816];
  const int tid = threadIdx.x, lane = tid & 63, pc = tid >> 6;
  const int g = lane >> 4, c = lane & 15;
  const int qt = 63 - (int)blockIdx.x;   // heavy q-tiles dispatch first
  const int bi = blockIdx.y;
  const int b = bi >> 4, hd = bi & 15;
  const size_t hoff = (size_t)bi * 2048 * 64;
  const short* Qh = Q + hoff;
  const short* Kh = K + hoff;
  const short* Vth = Vt + hoff;
  short* zbh = zb + (size_t)b * 2048 * 1024 + hd * 64;

  const int qw = qt * 32;
  const int P = qw + 32;
  const int csz = ((P + 511) >> 9) << 7;   // ceil(P/4) rounded up to 128
  const int p_lo = pc * csz;
  const int p_hi = min(p_lo + csz, P);

  short* pbuf = (short*)smem + pc * 4224;  // 32 rows x pitch 132
  float* mlb  = (float*)(smem + 33792);
  float* zm   = (float*)smem;

  const bf16x8* qp0 = (const bf16x8*)&Qh[(size_t)(qw + c) * 64];
  const bf16x8* qp1 = (const bf16x8*)&Qh[(size_t)(qw + 16 + c) * 64];
  bf16x8 aq[2][2];
  aq[0][0] = qp0[g]; aq[0][1] = qp0[4 + g];
  aq[1][0] = qp1[g]; aq[1][1] = qp1[4 + g];

  float m4[2][4], l4[2][4];
  f32x4 zacc[2][4] = {};
#pragma unroll
  for (int rb = 0; rb < 2; ++rb)
#pragma unroll
    for (int r = 0; r < 4; ++r) { m4[rb][r] = -1e30f; l4[rb][r] = 0.0f; }

  for (int p0 = p_lo; p0 < p_hi; p0 += 128) {
    bf16x8 k0[8], k1[8];
#pragma unroll
    for (int kb = 0; kb < 8; ++kb) {
      int row = p0 + kb * 16 + c;
      row = row < 2047 ? row : 2047;   // clamp; masked below via p<=q
      const bf16x8* kp = (const bf16x8*)&Kh[(size_t)row * 64];
      k0[kb] = kp[g]; k1[kb] = kp[4 + g];
    }
    const bool needmask = (p0 + 128 > qw);   // wave-uniform
#pragma unroll
    for (int rb = 0; rb < 2; ++rb) {
      f32x4 s[8];
      __builtin_amdgcn_s_setprio(1);
#pragma unroll
      for (int kb = 0; kb < 8; ++kb) {
        f32x4 z4 = {0.0f, 0.0f, 0.0f, 0.0f};
        z4 = mfma16(aq[rb][0], k0[kb], z4);
        s[kb] = mfma16(aq[rb][1], k1[kb], z4);
      }
      __builtin_amdgcn_s_setprio(0);
#pragma unroll
      for (int r = 0; r < 4; ++r) {
        const int q = qw + rb * 16 + g * 4 + r;
        float v[8];
        if (needmask) {
#pragma unroll
          for (int kb = 0; kb < 8; ++kb)
            v[kb] = (p0 + kb * 16 + c <= q) ? s[kb][r] * 0.125f : -1e30f;
        } else {
#pragma unroll
          for (int kb = 0; kb < 8; ++kb) v[kb] = s[kb][r] * 0.125f;
        }
        float mx = fmaxf(fmaxf(fmaxf(v[0], v[1]), fmaxf(v[2], v[3])),
                         fmaxf(fmaxf(v[4], v[5]), fmaxf(v[6], v[7])));
#pragma unroll
        for (int off = 1; off < 16; off <<= 1)
          mx = fmaxf(mx, __shfl_xor(mx, off));   // row-uniform across c-lanes
        const float mn = fmaxf(m4[rb][r], mx);
        const float fac = __expf(m4[rb][r] - mn);
        m4[rb][r] = mn;
        float lsum = 0.0f;
        if (needmask) {
#pragma unroll
          for (int kb = 0; kb < 8; ++kb) {
            const int p = p0 + kb * 16 + c;
            const float e = (p <= q) ? __expf(v[kb] - mn) : 0.0f;
            lsum += e;
            pbuf[(rb * 16 + g * 4 + r) * 132 + kb * 16 + c] = f2bf(e);
          }
        } else {
#pragma unroll
          for (int kb = 0; kb < 8; ++kb) {
            const float e = __expf(v[kb] - mn);
            lsum += e;
            pbuf[(rb * 16 + g * 4 + r) * 132 + kb * 16 + c] = f2bf(e);
          }
        }
        l4[rb][r] = l4[rb][r] * fac + lsum;
#pragma unroll
        for (int hb = 0; hb < 4; ++hb) zacc[rb][hb][r] *= fac;
      }
    }
    // PV: pa from pbuf (two 8B reads, 8B-aligned at pitch 132), bv from Vt
    __builtin_amdgcn_s_setprio(1);
#pragma unroll
    for (int j = 0; j < 4; ++j) {
      const short4v p0lo = *(const short4v*)&pbuf[c * 132 + j * 32 + g * 8];
      const short4v p0hi = *(const short4v*)&pbuf[c * 132 + j * 32 + g * 8 + 4];
      const short4v p1lo = *(const short4v*)&pbuf[(16 + c) * 132 + j * 32 + g * 8];
      const short4v p1hi = *(const short4v*)&pbuf[(16 + c) * 132 + j * 32 + g * 8 + 4];
      const bf16x8 pa0 = __builtin_shufflevector(p0lo, p0hi, 0, 1, 2, 3, 4, 5, 6, 7);
      const bf16x8 pa1 = __builtin_shufflevector(p1lo, p1hi, 0, 1, 2, 3, 4, 5, 6, 7);
#pragma unroll
      for (int hb = 0; hb < 4; ++hb) {
        const bf16x8 bv =
            *(const bf16x8*)&Vth[(size_t)(hb * 16 + c) * 2048 + p0 + j * 32 + g * 8];
        zacc[0][hb] = mfma16(pa0, bv, zacc[0][hb]);
        zacc[1][hb] = mfma16(pa1, bv, zacc[1][hb]);
      }
    }
    __builtin_amdgcn_s_setprio(0);
  }

  // cross-lane l sum (m already row-uniform)
#pragma unroll
  for (int rb = 0; rb < 2; ++rb)
#pragma unroll
    for (int r = 0; r < 4; ++r)
#pragma unroll
      for (int off = 1; off < 16; off <<= 1)
        l4[rb][r] += __shfl_xor(l4[rb][r], off);

  if (c == 0) {
#pragma unroll
    for (int rb = 0; rb < 2; ++rb)
#pragma unroll
      for (int r = 0; r < 4; ++r) {
        mlb[(pc * 32 + rb * 16 + g * 4 + r) * 2 + 0] = m4[rb][r];
        mlb[(pc * 32 + rb * 16 + g * 4 + r) * 2 + 1] = l4[rb][r];
      }
  }
  __syncthreads();  // pbuf dead in all waves; mlb visible

  // phase C: m-aware flash combine of the 4 chunk partials
  if (pc != 0) {
#pragma unroll
    for (int rb = 0; rb < 2; ++rb)
#pragma unroll
      for (int hb = 0; hb < 4; ++hb)
#pragma unroll
        for (int r = 0; r < 4; ++r)
          zm[((pc - 1) * 32 + rb * 16 + g * 4 + r) * 68 + hb * 16 + c] = zacc[rb][hb][r];
  }
  __syncthreads();
  if (pc == 0) {
#pragma unroll
    for (int rb = 0; rb < 2; ++rb)
#pragma unroll
      for (int r = 0; r < 4; ++r) {
        const int row = rb * 16 + g * 4 + r;
        float M = -1e30f;
#pragma unroll
        for (int j = 0; j < 4; ++j) M = fmaxf(M, mlb[(j * 32 + row) * 2 + 0]);
        float w[4], L = 0.0f;
#pragma unroll
        for (int j = 0; j < 4; ++j) {
          w[j] = __expf(mlb[(j * 32 + row) * 2 + 0] - M);
          L += mlb[(j * 32 + row) * 2 + 1] * w[j];
        }
        const float iL = 1.0f / L;
#pragma unroll
        for (int hb = 0; hb < 4; ++hb) {
          float z = zacc[rb][hb][r] * w[0];
#pragma unroll
          for (int j = 1; j < 4; ++j)
            z += zm[((j - 1) * 32 + row) * 68 + hb * 16 + c] * w[j];
          zbh[(size_t)(qw + row) * 1024 + hb * 16 + c] = f2bf(z * iL);
        }
        if (c == 0)
          ((float2*)ml)[(size_t)bi * 2048 + qw + row] = make_float2(M, iL);
      }
  }
}

// ---------------- att_write: materialize att, massively parallel -----------
__global__ __launch_bounds__(256) void att_write(
    const short* __restrict__ Q, const short* __restrict__ K,
    const float* __restrict__ ml, float* __restrict__ att) {
  __shared__ float fbuf_s[4][16 * 36];
  const int tid = threadIdx.x, lane = tid & 63, wave = tid >> 6;
  const int g = lane >> 4, c = lane & 15;
  const int qt = blockIdx.x, pt = blockIdx.y, bi = blockIdx.z;
  const int qs = wave >> 1, ph = wave & 1;
  const int qw = qt * 32 + qs * 16;
  const int pb = pt * 256 + ph * 128;
  float* atth = att + (size_t)bi * 2048 * 2048;
  const int r0 = lane >> 3, c4 = (lane & 7) * 4;

  if (pb > qw + 15) {  // strip entirely above the diagonal: pure zeros
    const f32x4 zf = {0.0f, 0.0f, 0.0f, 0.0f};
#pragma unroll
    for (int j = 0; j < 4; ++j) {
      __builtin_nontemporal_store(zf, (f32x4*)&atth[(size_t)(qw + r0) * 2048 + pb + j * 32 + c4]);
      __builtin_nontemporal_store(zf, (f32x4*)&atth[(size_t)(qw + 8 + r0) * 2048 + pb + j * 32 + c4]);
    }
    return;
  }

  const size_t hoff = (size_t)bi * 2048 * 64;
  const short* Qh = Q + hoff;
  const short* Kh = K + hoff;
  const bf16x8* qp = (const bf16x8*)&Qh[(size_t)(qw + c) * 64];
  const bf16x8 aq0 = qp[g], aq1 = qp[4 + g];
  float m4[4], il[4];
#pragma unroll
  for (int r = 0; r < 4; ++r) {
    const float2 t = ((const float2*)ml)[(size_t)bi * 2048 + qw + g * 4 + r];
    m4[r] = t.x; il[r] = t.y;
  }
  float* fbuf = fbuf_s[wave];
  for (int p0 = pb; p0 < pb + 128; p0 += 32) {
    const bf16x8* kp0 = (const bf16x8*)&Kh[(size_t)(p0 + c) * 64];
    const bf16x8* kp1 = (const bf16x8*)&Kh[(size_t)(p0 + 16 + c) * 64];
    f32x4 s0 = {0.0f, 0.0f, 0.0f, 0.0f}, s1 = {0.0f, 0.0f, 0.0f, 0.0f};
    s0 = mfma16(aq0, kp0[g], s0);
    s0 = mfma16(aq1, kp0[4 + g], s0);
    s1 = mfma16(aq0, kp1[g], s1);
    s1 = mfma16(aq1, kp1[4 + g], s1);
#pragma unroll
    for (int f = 0; f < 2; ++f) {
      const f32x4& ss = f ? s1 : s0;
#pragma unroll
      for (int r = 0; r < 4; ++r) {
        const int q = qw + g * 4 + r, p = p0 + f * 16 + c;
        const float e = (p <= q) ? __expf(ss[r] * 0.125f - m4[r]) * il[r] : 0.0f;
        fbuf[(g * 4 + r) * 36 + f * 16 + c] = e;
      }
    }
    const f32x4 v0 = *(const f32x4*)&fbuf[r0 * 36 + c4];
    const f32x4 v1 = *(const f32x4*)&fbuf[(8 + r0) * 36 + c4];
    __builtin_nontemporal_store(v0, (f32x4*)&atth[(size_t)(qw + r0) * 2048 + p0 + c4]);
    __builtin_nontemporal_store(v1, (f32x4*)&atth[(size_t)(qw + 8 + r0) * 2048 + p0 + c4]);
  }
}

// ---------------- launch ----------------
extern "C" void kernel_launch(void* const* d_in, const int* in_sizes, int n_in,
                              void* d_out, int out_size, void* d_ws, size_t ws_size,
                              hipStream_t stream) {
  (void)in_sizes; (void)n_in; (void)out_size; (void)ws_size;
  const float* x    = (const float*)d_in[0];
  const float* WQ   = (const float*)d_in[1];
  const float* WK   = (const float*)d_in[2];
  const float* WV   = (const float*)d_in[3];
  const float* WO   = (const float*)d_in[4];
  const float* lnaw = (const float*)d_in[5];
  const float* lnab = (const float*)d_in[6];
  const float* lnmw = (const float*)d_in[7];
  const float* lnmb = (const float*)d_in[8];
  const float* w1   = (const float*)d_in[9];
  const float* b1   = (const float*)d_in[10];
  const float* w2   = (const float*)d_in[11];
  const float* b2   = (const float*)d_in[12];

  char* ws = (char*)d_ws;
  const size_t MB = 1024 * 1024;
  short* Wqkv = (short*)(ws + 0 * MB);   // 6MB: packed [3072][1024] bf16
  short* Wob  = (short*)(ws + 6 * MB);   // 2MB
  short* w1b  = (short*)(ws + 8 * MB);   // 8MB
  short* w2b  = (short*)(ws + 16 * MB);  // 8MB
  short* yb   = (short*)(ws + 24 * MB);  // 8MB (LN1 out; reused for LN2 out)
  short* Qb   = (short*)(ws + 32 * MB);  // 8MB  } contiguous: fused QKV
  short* Kb   = (short*)(ws + 40 * MB);  // 8MB  } scatter writes sel*4M
  short* Vb   = (short*)(ws + 48 * MB);  // 8MB  }
  short* Vtb  = (short*)(ws + 56 * MB);  // 8MB
  short* zbuf = (short*)(ws + 64 * MB);  // 8MB
  float* x1   = (float*)(ws + 72 * MB);  // 16MB (written after att_write reads mlw)
  float* mlw  = (float*)(ws + 72 * MB);  // 512KB, overlaps x1 (stream-ordered:
                                         // att_write consumes mlw BEFORE gemm1
                                         // writes x1)
  short* hb   = (short*)(ws + 32 * MB);  // 32MB, reuses Q/K/V/Vt (dead by MLP1)

  float* outx = (float*)d_out;
  float* att  = outx + (size_t)2 * 2048 * 1024;  // output 1 region

  // weight converts + LN1 in one dispatch
  prep_all<<<dim3(19456), dim3(256), 0, stream>>>(
      WQ, WK, WV, WO, w1, w2, x, lnaw, lnab, Wqkv, Wob, w1b, w2b, yb);

  // fused QKV projection: 128x128 single-buffer (R17 best)
  gemm_bf16k<0, 128, 128, false><<<dim3(24, 32), dim3(256), 0, stream>>>(
      yb, Wqkv, nullptr, Qb, nullptr, nullptr, 4096, 3072, 1024);

  // V transpose for PV B-operand
  transpose_v<<<dim3(32, 32), dim3(256), 0, stream>>>(Vb, Vtb);

  // attention stats + z (single-pass online flash + setprio)
  attn_flash<<<dim3(64, 32), dim3(256), 0, stream>>>(Qb, Kb, Vtb, mlw, zbuf);

  // att materialization (embarrassingly parallel, store-BW-bound)
  att_write<<<dim3(64, 8, 32), dim3(256), 0, stream>>>(Qb, Kb, mlw, att);

  // output projection + residual -> x1; 128x64 DBUF (thin-TLP shape)
  gemm_bf16k<1, 128, 64, true><<<dim3(16, 32), dim3(256), 0, stream>>>(
      zbuf, Wob, x1, nullptr, x, nullptr, 4096, 1024, 1024);

  // LN2
  ln_kernel<<<dim3(4096), dim3(256), 0, stream>>>(x1, lnmw, lnmb, yb);

  // MLP1: 128x128 single-buffer (R17 best)
  gemm_bf16k<2, 128, 128, false><<<dim3(32, 32), dim3(256), 0, stream>>>(
      yb, w1b, nullptr, hb, nullptr, b1, 4096, 4096, 1024);
  // MLP2: 128x64 DBUF (thin-TLP shape)
  gemm_bf16k<3, 128, 64, true><<<dim3(16, 32), dim3(256), 0, stream>>>(
      hb, w2b, outx, nullptr, x1, b2, 4096, 1024, 4096);
}

// Round 20
// 417.421 us; speedup vs baseline: 1.1152x; 1.0811x over previous
//
#include <hip/hip_runtime.h>
#include <hip/hip_bf16.h>
#include <stdint.h>

typedef __attribute__((ext_vector_type(8))) short bf16x8;
typedef __attribute__((ext_vector_type(4))) short short4v;
typedef __attribute__((ext_vector_type(4))) float f32x4;

#define GLOAD16(g, s) __builtin_amdgcn_global_load_lds( \
    (const __attribute__((address_space(1))) void*)(g),  \
    (__attribute__((address_space(3))) void*)(s), 16, 0, 0)

static __device__ __forceinline__ short f2bf(float f) {
  unsigned u = __builtin_bit_cast(unsigned, f);
  u += 0x7fffu + ((u >> 16) & 1u);
  return (short)(u >> 16);
}

static __device__ __forceinline__ f32x4 mfma16(bf16x8 a, bf16x8 b, f32x4 c) {
  return __builtin_amdgcn_mfma_f32_16x16x32_bf16(a, b, c, 0, 0, 0);
}

// ---------------- prep_all: weight converts + LN1 in ONE dispatch ----------
__global__ __launch_bounds__(256) void prep_all(
    const float* __restrict__ WQ, const float* __restrict__ WK,
    const float* __restrict__ WV, const float* __restrict__ WO,
    const float* __restrict__ w1, const float* __restrict__ w2,
    const float* __restrict__ x, const float* __restrict__ lnw,
    const float* __restrict__ lnb,
    short* __restrict__ Wqkv, short* __restrict__ Wob,
    short* __restrict__ w1b, short* __restrict__ w2b,
    short* __restrict__ yb) {
  __shared__ float red[8];
  const int bi = blockIdx.x, tid = threadIdx.x;
  if (bi < 3072) {
    const float* src = bi < 1024 ? WQ : (bi < 2048 ? WK : WV);
    const float4 v = ((const float4*)(src + (size_t)(bi & 1023) * 1024))[tid];
    short4v o;
    o[0] = f2bf(v.x); o[1] = f2bf(v.y); o[2] = f2bf(v.z); o[3] = f2bf(v.w);
    ((short4v*)(Wqkv + (size_t)bi * 1024))[tid] = o;
  } else if (bi < 7168) {
    const int i = (bi - 3072) * 256 + tid;
    const float4 v = ((const float4*)w1)[i];
    short4v o;
    o[0] = f2bf(v.x); o[1] = f2bf(v.y); o[2] = f2bf(v.z); o[3] = f2bf(v.w);
    ((short4v*)w1b)[i] = o;
  } else if (bi < 11264) {
    const int i = (bi - 7168) * 256 + tid;
    const float4 v = ((const float4*)w2)[i];
    short4v o;
    o[0] = f2bf(v.x); o[1] = f2bf(v.y); o[2] = f2bf(v.z); o[3] = f2bf(v.w);
    ((short4v*)w2b)[i] = o;
  } else if (bi < 15360) {
    const int idx = (bi - 11264) * 256 + tid;  // [D][H*DH] out
    const int d = idx >> 10, cc = idx & 1023;
    const int i = cc >> 6, h = cc & 63;
    Wob[idx] = f2bf(WO[((size_t)d * 64 + h) * 16 + i]);
  } else {
    const int row = bi - 15360;
    const int lane = tid & 63, wave = tid >> 6;
    const float4 xv = *(const float4*)&x[(size_t)row * 1024 + tid * 4];
    float s1 = xv.x + xv.y + xv.z + xv.w;
    float s2 = xv.x * xv.x + xv.y * xv.y + xv.z * xv.z + xv.w * xv.w;
#pragma unroll
    for (int off = 1; off < 64; off <<= 1) {
      s1 += __shfl_xor(s1, off);
      s2 += __shfl_xor(s2, off);
    }
    if (lane == 0) { red[wave] = s1; red[4 + wave] = s2; }
    __syncthreads();
    s1 = red[0] + red[1] + red[2] + red[3];
    s2 = red[4] + red[5] + red[6] + red[7];
    const float mu = s1 * (1.0f / 1024.0f);
    const float var = s2 * (1.0f / 1024.0f) - mu * mu;
    const float rs = rsqrtf(var + 1e-5f);
    const float4 wv = *(const float4*)&lnw[tid * 4];
    const float4 bv = *(const float4*)&lnb[tid * 4];
    short4v o;
    o[0] = f2bf((xv.x - mu) * rs * wv.x + bv.x);
    o[1] = f2bf((xv.y - mu) * rs * wv.y + bv.y);
    o[2] = f2bf((xv.z - mu) * rs * wv.z + bv.z);
    o[3] = f2bf((xv.w - mu) * rs * wv.w + bv.w);
    *(short4v*)&yb[(size_t)row * 1024 + tid * 4] = o;
  }
}

// ---------------- LayerNorm standalone (LN2) ----------------
__global__ __launch_bounds__(256) void ln_kernel(const float* __restrict__ x,
                                                 const float* __restrict__ w,
                                                 const float* __restrict__ b,
                                                 short* __restrict__ y) {
  const int row = blockIdx.x, tid = threadIdx.x;
  const int lane = tid & 63, wave = tid >> 6;
  const float4 xv = *(const float4*)&x[(size_t)row * 1024 + tid * 4];
  float s1 = xv.x + xv.y + xv.z + xv.w;
  float s2 = xv.x * xv.x + xv.y * xv.y + xv.z * xv.z + xv.w * xv.w;
#pragma unroll
  for (int off = 1; off < 64; off <<= 1) {
    s1 += __shfl_xor(s1, off);
    s2 += __shfl_xor(s2, off);
  }
  __shared__ float red[8];
  if (lane == 0) { red[wave] = s1; red[4 + wave] = s2; }
  __syncthreads();
  s1 = red[0] + red[1] + red[2] + red[3];
  s2 = red[4] + red[5] + red[6] + red[7];
  const float mu = s1 * (1.0f / 1024.0f);
  const float var = s2 * (1.0f / 1024.0f) - mu * mu;
  const float rs = rsqrtf(var + 1e-5f);
  const float4 wv = *(const float4*)&w[tid * 4];
  const float4 bv = *(const float4*)&b[tid * 4];
  short4v o;
  o[0] = f2bf((xv.x - mu) * rs * wv.x + bv.x);
  o[1] = f2bf((xv.y - mu) * rs * wv.y + bv.y);
  o[2] = f2bf((xv.z - mu) * rs * wv.z + bv.z);
  o[3] = f2bf((xv.w - mu) * rs * wv.w + bv.w);
  *(short4v*)&y[(size_t)row * 1024 + tid * 4] = o;
}

// ------- GEMM: C = A*Bw^T, bf16, fp32 acc, tile BMxBN -----
// Shape-conditional config (R17/R18 measured):
//   Large-N GEMMs (QKV N=3072, MLP1 N=4096): 128x128 single-buffer.
//   N=1024 GEMMs (WO-proj, MLP2): 128x64 DBUF (48KB -> 3 blocks/CU).
template <int MODE, int BM, int BN, bool DBUF>
__global__ __launch_bounds__(256) void gemm_bf16k(
    const short* __restrict__ A, const short* __restrict__ Bw,
    float* __restrict__ outF, short* __restrict__ outB,
    const float* __restrict__ resid, const float* __restrict__ bias,
    int M, int N, int K) {
  constexpr int RBM = BM / 2, RBN = BN / 2;
  constexpr int FM = RBM / 16, FN = RBN / 16;
  constexpr int TCA = BM / 8, TCB = BN / 8, TC = TCA + TCB;
  constexpr int NB = DBUF ? 2 : 1;
  __shared__ short As[NB][BM * 64];
  __shared__ short Bs[NB][BN * 64];
  const int tid = threadIdx.x, lane = tid & 63, wave = tid >> 6;
  const int nbx = gridDim.x, nwg = nbx * gridDim.y;
  int lid = (int)blockIdx.y * nbx + (int)blockIdx.x;
  lid = (lid & 7) * (nwg >> 3) + (lid >> 3);   // xcd-chunked remap (nwg%8==0)
  const int m0 = (lid / nbx) * BM, n0 = (lid % nbx) * BN;
  const int wm = (wave & 1) * RBM, wn = (wave >> 1) * RBN;
  const int lr = lane >> 3;        // row within 8-row chunk
  const int lc = (lane & 7) * 8;   // elem col within chunk row
  f32x4 acc[FM][FN] = {};

  auto stage = [&](int d, int kt) {
#pragma unroll
    for (int i = 0; i < TC / 4; ++i) {
      const int ch = i * 4 + wave;
      if (ch < TCA) {
        GLOAD16(A + (size_t)(m0 + ch * 8 + lr) * K + kt + lc, &As[d][ch * 512]);
      } else {
        const int cb = ch - TCA;
        GLOAD16(Bw + (size_t)(n0 + cb * 8 + lr) * K + kt + lc, &Bs[d][cb * 512]);
      }
    }
  };
  auto compute = [&](int d) {
#pragma unroll
    for (int kk = 0; kk < 64; kk += 32) {
      bf16x8 af[FM], bfr[FN];
#pragma unroll
      for (int i2 = 0; i2 < FM; ++i2)
        af[i2] = *(const bf16x8*)&As[d][(wm + i2 * 16 + (lane & 15)) * 64 + kk + (lane >> 4) * 8];
#pragma unroll
      for (int j2 = 0; j2 < FN; ++j2)
        bfr[j2] = *(const bf16x8*)&Bs[d][(wn + j2 * 16 + (lane & 15)) * 64 + kk + (lane >> 4) * 8];
#pragma unroll
      for (int i2 = 0; i2 < FM; ++i2)
#pragma unroll
        for (int j2 = 0; j2 < FN; ++j2)
          acc[i2][j2] = mfma16(af[i2], bfr[j2], acc[i2][j2]);
    }
  };

  const int nt = K >> 6;
  if constexpr (DBUF) {
    stage(0, 0);
    __syncthreads();
    for (int t = 0; t < nt; ++t) {
      const int cur = t & 1;
      if (t + 1 < nt) stage(cur ^ 1, (t + 1) << 6);
      compute(cur);
      __syncthreads();
    }
  } else {
    for (int t = 0; t < nt; ++t) {
      stage(0, t << 6);
      __syncthreads();
      compute(0);
      __syncthreads();
    }
  }

#pragma unroll
  for (int i2 = 0; i2 < FM; ++i2)
#pragma unroll
    for (int j2 = 0; j2 < FN; ++j2)
#pragma unroll
      for (int r = 0; r < 4; ++r) {
        const int m = m0 + wm + i2 * 16 + (lane >> 4) * 4 + r;
        const int n = n0 + wn + j2 * 16 + (lane & 15);
        const float v = acc[i2][j2][r];
        if (MODE == 0) {
          const size_t oi = (size_t)(n >> 10) * 4194304 +
              ((size_t)((m >> 11) * 16 + ((n & 1023) >> 6)) * 2048 + (m & 2047)) * 64 +
              (n & 63);
          outB[oi] = f2bf(v);
        } else if (MODE == 1) {
          outF[(size_t)m * N + n] = resid[(size_t)m * N + n] + v;
        } else if (MODE == 2) {
          const float t2 = v + bias[n];
          outB[(size_t)m * N + n] = f2bf(t2 > 0.0f ? t2 : 0.0f);
        } else {
          outF[(size_t)m * N + n] = resid[(size_t)m * N + n] + v + bias[n];
        }
      }
}

// ---------------- V transpose: [BH][S][64] -> [BH][64][S] ----------------
__global__ __launch_bounds__(256) void transpose_v(const short* __restrict__ V,
                                                   short* __restrict__ Vt) {
  __shared__ short t[64][72];
  const int bi = blockIdx.y;
  const int p0 = blockIdx.x * 64;
  const short* Vh = V + (size_t)bi * 2048 * 64;
  short* Vth = Vt + (size_t)bi * 64 * 2048;
  const int tid = threadIdx.x;
  {
    const int pr = tid >> 2, h0 = (tid & 3) * 16;
    const bf16x8* src = (const bf16x8*)&Vh[(size_t)(p0 + pr) * 64 + h0];
    bf16x8 v0 = src[0], v1 = src[1];
#pragma unroll
    for (int j = 0; j < 8; ++j) { t[pr][h0 + j] = v0[j]; t[pr][h0 + 8 + j] = v1[j]; }
  }
  __syncthreads();
  {
    const int hr = tid >> 2, pq = (tid & 3) * 16;
    bf16x8 o0, o1;
#pragma unroll
    for (int j = 0; j < 8; ++j) { o0[j] = t[pq + j][hr]; o1[j] = t[pq + 8 + j][hr]; }
    *(bf16x8*)&Vth[(size_t)hr * 2048 + p0 + pq] = o0;
    *(bf16x8*)&Vth[(size_t)hr * 2048 + p0 + pq + 8] = o1;
  }
}

// ---- attn_flash v4 + T5 setprio + XCD-chunked head locality ----
// New this round: bijective remap of the 2048-block grid so each XCD's
// round-robin share is a CONTIGUOUS lid' chunk = 4 heads (2MB K/V+Q),
// fitting the 4MB per-XCD L2 (was: all 32 heads / 16MB -> L2 thrash; K-load
// latency L2-miss ~450cyc vs hit ~200cyc on the exposed serial chain).
__global__ __launch_bounds__(256, 2) void attn_flash(
    const short* __restrict__ Q, const short* __restrict__ K,
    const short* __restrict__ Vt, float* __restrict__ ml,
    short* __restrict__ zb) {
  __shared__ __align__(16) char smem[34816];
  const int tid = threadIdx.x, lane = tid & 63, pc = tid >> 6;
  const int g = lane >> 4, c = lane & 15;
  int lid = (int)blockIdx.y * 64 + (int)blockIdx.x;   // [0, 2048)
  lid = (lid & 7) * 256 + (lid >> 3);                 // XCD chunk: 4 heads/XCD
  const int bi = lid >> 6;
  const int qt = 63 - (lid & 63);        // heavy q-tiles first within chunk
  const int b = bi >> 4, hd = bi & 15;
  const size_t hoff = (size_t)bi * 2048 * 64;
  const short* Qh = Q + hoff;
  const short* Kh = K + hoff;
  const short* Vth = Vt + hoff;
  short* zbh = zb + (size_t)b * 2048 * 1024 + hd * 64;

  const int qw = qt * 32;
  const int P = qw + 32;
  const int csz = ((P + 511) >> 9) << 7;   // ceil(P/4) rounded up to 128
  const int p_lo = pc * csz;
  const int p_hi = min(p_lo + csz, P);

  short* pbuf = (short*)smem + pc * 4224;  // 32 rows x pitch 132
  float* mlb  = (float*)(smem + 33792);
  float* zm   = (float*)smem;

  const bf16x8* qp0 = (const bf16x8*)&Qh[(size_t)(qw + c) * 64];
  const bf16x8* qp1 = (const bf16x8*)&Qh[(size_t)(qw + 16 + c) * 64];
  bf16x8 aq[2][2];
  aq[0][0] = qp0[g]; aq[0][1] = qp0[4 + g];
  aq[1][0] = qp1[g]; aq[1][1] = qp1[4 + g];

  float m4[2][4], l4[2][4];
  f32x4 zacc[2][4] = {};
#pragma unroll
  for (int rb = 0; rb < 2; ++rb)
#pragma unroll
    for (int r = 0; r < 4; ++r) { m4[rb][r] = -1e30f; l4[rb][r] = 0.0f; }

  for (int p0 = p_lo; p0 < p_hi; p0 += 128) {
    bf16x8 k0[8], k1[8];
#pragma unroll
    for (int kb = 0; kb < 8; ++kb) {
      int row = p0 + kb * 16 + c;
      row = row < 2047 ? row : 2047;   // clamp; masked below via p<=q
      const bf16x8* kp = (const bf16x8*)&Kh[(size_t)row * 64];
      k0[kb] = kp[g]; k1[kb] = kp[4 + g];
    }
    const bool needmask = (p0 + 128 > qw);   // wave-uniform
#pragma unroll
    for (int rb = 0; rb < 2; ++rb) {
      f32x4 s[8];
      __builtin_amdgcn_s_setprio(1);
#pragma unroll
      for (int kb = 0; kb < 8; ++kb) {
        f32x4 z4 = {0.0f, 0.0f, 0.0f, 0.0f};
        z4 = mfma16(aq[rb][0], k0[kb], z4);
        s[kb] = mfma16(aq[rb][1], k1[kb], z4);
      }
      __builtin_amdgcn_s_setprio(0);
#pragma unroll
      for (int r = 0; r < 4; ++r) {
        const int q = qw + rb * 16 + g * 4 + r;
        float v[8];
        if (needmask) {
#pragma unroll
          for (int kb = 0; kb < 8; ++kb)
            v[kb] = (p0 + kb * 16 + c <= q) ? s[kb][r] * 0.125f : -1e30f;
        } else {
#pragma unroll
          for (int kb = 0; kb < 8; ++kb) v[kb] = s[kb][r] * 0.125f;
        }
        float mx = fmaxf(fmaxf(fmaxf(v[0], v[1]), fmaxf(v[2], v[3])),
                         fmaxf(fmaxf(v[4], v[5]), fmaxf(v[6], v[7])));
#pragma unroll
        for (int off = 1; off < 16; off <<= 1)
          mx = fmaxf(mx, __shfl_xor(mx, off));   // row-uniform across c-lanes
        const float mn = fmaxf(m4[rb][r], mx);
        const float fac = __expf(m4[rb][r] - mn);
        m4[rb][r] = mn;
        float lsum = 0.0f;
        if (needmask) {
#pragma unroll
          for (int kb = 0; kb < 8; ++kb) {
            const int p = p0 + kb * 16 + c;
            const float e = (p <= q) ? __expf(v[kb] - mn) : 0.0f;
            lsum += e;
            pbuf[(rb * 16 + g * 4 + r) * 132 + kb * 16 + c] = f2bf(e);
          }
        } else {
#pragma unroll
          for (int kb = 0; kb < 8; ++kb) {
            const float e = __expf(v[kb] - mn);
            lsum += e;
            pbuf[(rb * 16 + g * 4 + r) * 132 + kb * 16 + c] = f2bf(e);
          }
        }
        l4[rb][r] = l4[rb][r] * fac + lsum;
#pragma unroll
        for (int hb = 0; hb < 4; ++hb) zacc[rb][hb][r] *= fac;
      }
    }
    // PV: pa from pbuf (two 8B reads, 8B-aligned at pitch 132), bv from Vt
    __builtin_amdgcn_s_setprio(1);
#pragma unroll
    for (int j = 0; j < 4; ++j) {
      const short4v p0lo = *(const short4v*)&pbuf[c * 132 + j * 32 + g * 8];
      const short4v p0hi = *(const short4v*)&pbuf[c * 132 + j * 32 + g * 8 + 4];
      const short4v p1lo = *(const short4v*)&pbuf[(16 + c) * 132 + j * 32 + g * 8];
      const short4v p1hi = *(const short4v*)&pbuf[(16 + c) * 132 + j * 32 + g * 8 + 4];
      const bf16x8 pa0 = __builtin_shufflevector(p0lo, p0hi, 0, 1, 2, 3, 4, 5, 6, 7);
      const bf16x8 pa1 = __builtin_shufflevector(p1lo, p1hi, 0, 1, 2, 3, 4, 5, 6, 7);
#pragma unroll
      for (int hb = 0; hb < 4; ++hb) {
        const bf16x8 bv =
            *(const bf16x8*)&Vth[(size_t)(hb * 16 + c) * 2048 + p0 + j * 32 + g * 8];
        zacc[0][hb] = mfma16(pa0, bv, zacc[0][hb]);
        zacc[1][hb] = mfma16(pa1, bv, zacc[1][hb]);
      }
    }
    __builtin_amdgcn_s_setprio(0);
  }

  // cross-lane l sum (m already row-uniform)
#pragma unroll
  for (int rb = 0; rb < 2; ++rb)
#pragma unroll
    for (int r = 0; r < 4; ++r)
#pragma unroll
      for (int off = 1; off < 16; off <<= 1)
        l4[rb][r] += __shfl_xor(l4[rb][r], off);

  if (c == 0) {
#pragma unroll
    for (int rb = 0; rb < 2; ++rb)
#pragma unroll
      for (int r = 0; r < 4; ++r) {
        mlb[(pc * 32 + rb * 16 + g * 4 + r) * 2 + 0] = m4[rb][r];
        mlb[(pc * 32 + rb * 16 + g * 4 + r) * 2 + 1] = l4[rb][r];
      }
  }
  __syncthreads();  // pbuf dead in all waves; mlb visible

  // phase C: m-aware flash combine of the 4 chunk partials
  if (pc != 0) {
#pragma unroll
    for (int rb = 0; rb < 2; ++rb)
#pragma unroll
      for (int hb = 0; hb < 4; ++hb)
#pragma unroll
        for (int r = 0; r < 4; ++r)
          zm[((pc - 1) * 32 + rb * 16 + g * 4 + r) * 68 + hb * 16 + c] = zacc[rb][hb][r];
  }
  __syncthreads();
  if (pc == 0) {
#pragma unroll
    for (int rb = 0; rb < 2; ++rb)
#pragma unroll
      for (int r = 0; r < 4; ++r) {
        const int row = rb * 16 + g * 4 + r;
        float M = -1e30f;
#pragma unroll
        for (int j = 0; j < 4; ++j) M = fmaxf(M, mlb[(j * 32 + row) * 2 + 0]);
        float w[4], L = 0.0f;
#pragma unroll
        for (int j = 0; j < 4; ++j) {
          w[j] = __expf(mlb[(j * 32 + row) * 2 + 0] - M);
          L += mlb[(j * 32 + row) * 2 + 1] * w[j];
        }
        const float iL = 1.0f / L;
#pragma unroll
        for (int hb = 0; hb < 4; ++hb) {
          float z = zacc[rb][hb][r] * w[0];
#pragma unroll
          for (int j = 1; j < 4; ++j)
            z += zm[((j - 1) * 32 + row) * 68 + hb * 16 + c] * w[j];
          zbh[(size_t)(qw + row) * 1024 + hb * 16 + c] = f2bf(z * iL);
        }
        if (c == 0)
          ((float2*)ml)[(size_t)bi * 2048 + qw + row] = make_float2(M, iL);
      }
  }
}

// ---------------- att_write: materialize att, massively parallel -----------
__global__ __launch_bounds__(256) void att_write(
    const short* __restrict__ Q, const short* __restrict__ K,
    const float* __restrict__ ml, float* __restrict__ att) {
  __shared__ float fbuf_s[4][16 * 36];
  const int tid = threadIdx.x, lane = tid & 63, wave = tid >> 6;
  const int g = lane >> 4, c = lane & 15;
  const int qt = blockIdx.x, pt = blockIdx.y, bi = blockIdx.z;
  const int qs = wave >> 1, ph = wave & 1;
  const int qw = qt * 32 + qs * 16;
  const int pb = pt * 256 + ph * 128;
  float* atth = att + (size_t)bi * 2048 * 2048;
  const int r0 = lane >> 3, c4 = (lane & 7) * 4;

  if (pb > qw + 15) {  // strip entirely above the diagonal: pure zeros
    const f32x4 zf = {0.0f, 0.0f, 0.0f, 0.0f};
#pragma unroll
    for (int j = 0; j < 4; ++j) {
      __builtin_nontemporal_store(zf, (f32x4*)&atth[(size_t)(qw + r0) * 2048 + pb + j * 32 + c4]);
      __builtin_nontemporal_store(zf, (f32x4*)&atth[(size_t)(qw + 8 + r0) * 2048 + pb + j * 32 + c4]);
    }
    return;
  }

  const size_t hoff = (size_t)bi * 2048 * 64;
  const short* Qh = Q + hoff;
  const short* Kh = K + hoff;
  const bf16x8* qp = (const bf16x8*)&Qh[(size_t)(qw + c) * 64];
  const bf16x8 aq0 = qp[g], aq1 = qp[4 + g];
  float m4[4], il[4];
#pragma unroll
  for (int r = 0; r < 4; ++r) {
    const float2 t = ((const float2*)ml)[(size_t)bi * 2048 + qw + g * 4 + r];
    m4[r] = t.x; il[r] = t.y;
  }
  float* fbuf = fbuf_s[wave];
  for (int p0 = pb; p0 < pb + 128; p0 += 32) {
    const bf16x8* kp0 = (const bf16x8*)&Kh[(size_t)(p0 + c) * 64];
    const bf16x8* kp1 = (const bf16x8*)&Kh[(size_t)(p0 + 16 + c) * 64];
    f32x4 s0 = {0.0f, 0.0f, 0.0f, 0.0f}, s1 = {0.0f, 0.0f, 0.0f, 0.0f};
    s0 = mfma16(aq0, kp0[g], s0);
    s0 = mfma16(aq1, kp0[4 + g], s0);
    s1 = mfma16(aq0, kp1[g], s1);
    s1 = mfma16(aq1, kp1[4 + g], s1);
#pragma unroll
    for (int f = 0; f < 2; ++f) {
      const f32x4& ss = f ? s1 : s0;
#pragma unroll
      for (int r = 0; r < 4; ++r) {
        const int q = qw + g * 4 + r, p = p0 + f * 16 + c;
        const float e = (p <= q) ? __expf(ss[r] * 0.125f - m4[r]) * il[r] : 0.0f;
        fbuf[(g * 4 + r) * 36 + f * 16 + c] = e;
      }
    }
    const f32x4 v0 = *(const f32x4*)&fbuf[r0 * 36 + c4];
    const f32x4 v1 = *(const f32x4*)&fbuf[(8 + r0) * 36 + c4];
    __builtin_nontemporal_store(v0, (f32x4*)&atth[(size_t)(qw + r0) * 2048 + p0 + c4]);
    __builtin_nontemporal_store(v1, (f32x4*)&atth[(size_t)(qw + 8 + r0) * 2048 + p0 + c4]);
  }
}

// ---------------- launch ----------------
extern "C" void kernel_launch(void* const* d_in, const int* in_sizes, int n_in,
                              void* d_out, int out_size, void* d_ws, size_t ws_size,
                              hipStream_t stream) {
  (void)in_sizes; (void)n_in; (void)out_size; (void)ws_size;
  const float* x    = (const float*)d_in[0];
  const float* WQ   = (const float*)d_in[1];
  const float* WK   = (const float*)d_in[2];
  const float* WV   = (const float*)d_in[3];
  const float* WO   = (const float*)d_in[4];
  const float* lnaw = (const float*)d_in[5];
  const float* lnab = (const float*)d_in[6];
  const float* lnmw = (const float*)d_in[7];
  const float* lnmb = (const float*)d_in[8];
  const float* w1   = (const float*)d_in[9];
  const float* b1   = (const float*)d_in[10];
  const float* w2   = (const float*)d_in[11];
  const float* b2   = (const float*)d_in[12];

  char* ws = (char*)d_ws;
  const size_t MB = 1024 * 1024;
  short* Wqkv = (short*)(ws + 0 * MB);   // 6MB: packed [3072][1024] bf16
  short* Wob  = (short*)(ws + 6 * MB);   // 2MB
  short* w1b  = (short*)(ws + 8 * MB);   // 8MB
  short* w2b  = (short*)(ws + 16 * MB);  // 8MB
  short* yb   = (short*)(ws + 24 * MB);  // 8MB (LN1 out; reused for LN2 out)
  short* Qb   = (short*)(ws + 32 * MB);  // 8MB  } contiguous: fused QKV
  short* Kb   = (short*)(ws + 40 * MB);  // 8MB  } scatter writes sel*4M
  short* Vb   = (short*)(ws + 48 * MB);  // 8MB  }
  short* Vtb  = (short*)(ws + 56 * MB);  // 8MB
  short* zbuf = (short*)(ws + 64 * MB);  // 8MB
  float* x1   = (float*)(ws + 72 * MB);  // 16MB (written after att_write reads mlw)
  float* mlw  = (float*)(ws + 72 * MB);  // 512KB, overlaps x1 (stream-ordered:
                                         // att_write consumes mlw BEFORE gemm1
                                         // writes x1)
  short* hb   = (short*)(ws + 32 * MB);  // 32MB, reuses Q/K/V/Vt (dead by MLP1)

  float* outx = (float*)d_out;
  float* att  = outx + (size_t)2 * 2048 * 1024;  // output 1 region

  // weight converts + LN1 in one dispatch
  prep_all<<<dim3(19456), dim3(256), 0, stream>>>(
      WQ, WK, WV, WO, w1, w2, x, lnaw, lnab, Wqkv, Wob, w1b, w2b, yb);

  // fused QKV projection: 128x128 single-buffer (best measured)
  gemm_bf16k<0, 128, 128, false><<<dim3(24, 32), dim3(256), 0, stream>>>(
      yb, Wqkv, nullptr, Qb, nullptr, nullptr, 4096, 3072, 1024);

  // V transpose for PV B-operand
  transpose_v<<<dim3(32, 32), dim3(256), 0, stream>>>(Vb, Vtb);

  // attention stats + z (online flash + setprio + XCD head-locality)
  attn_flash<<<dim3(64, 32), dim3(256), 0, stream>>>(Qb, Kb, Vtb, mlw, zbuf);

  // att materialization (embarrassingly parallel, store-BW-bound)
  att_write<<<dim3(64, 8, 32), dim3(256), 0, stream>>>(Qb, Kb, mlw, att);

  // output projection + residual -> x1; 128x64 DBUF (thin-TLP shape)
  gemm_bf16k<1, 128, 64, true><<<dim3(16, 32), dim3(256), 0, stream>>>(
      zbuf, Wob, x1, nullptr, x, nullptr, 4096, 1024, 1024);

  // LN2
  ln_kernel<<<dim3(4096), dim3(256), 0, stream>>>(x1, lnmw, lnmb, yb);

  // MLP1: 128x128 single-buffer (best measured)
  gemm_bf16k<2, 128, 128, false><<<dim3(32, 32), dim3(256), 0, stream>>>(
      yb, w1b, nullptr, hb, nullptr, b1, 4096, 4096, 1024);
  // MLP2: 128x64 DBUF (thin-TLP shape)
  gemm_bf16k<3, 128, 64, true><<<dim3(16, 32), dim3(256), 0, stream>>>(
      hb, w2b, outx, nullptr, x1, b2, 4096, 1024, 4096);
}

// Round 21
// 408.667 us; speedup vs baseline: 1.1391x; 1.0214x over previous
//
#include <hip/hip_runtime.h>
#include <hip/hip_bf16.h>
#include <stdint.h>

typedef __attribute__((ext_vector_type(8))) short bf16x8;
typedef __attribute__((ext_vector_type(4))) short short4v;
typedef __attribute__((ext_vector_type(4))) float f32x4;

#define GLOAD16(g, s) __builtin_amdgcn_global_load_lds( \
    (const __attribute__((address_space(1))) void*)(g),  \
    (__attribute__((address_space(3))) void*)(s), 16, 0, 0)

static __device__ __forceinline__ short f2bf(float f) {
  unsigned u = __builtin_bit_cast(unsigned, f);
  u += 0x7fffu + ((u >> 16) & 1u);
  return (short)(u >> 16);
}

static __device__ __forceinline__ f32x4 mfma16(bf16x8 a, bf16x8 b, f32x4 c) {
  return __builtin_amdgcn_mfma_f32_16x16x32_bf16(a, b, c, 0, 0, 0);
}

// ---------------- prep_all: weight converts + LN1 in ONE dispatch ----------
__global__ __launch_bounds__(256) void prep_all(
    const float* __restrict__ WQ, const float* __restrict__ WK,
    const float* __restrict__ WV, const float* __restrict__ WO,
    const float* __restrict__ w1, const float* __restrict__ w2,
    const float* __restrict__ x, const float* __restrict__ lnw,
    const float* __restrict__ lnb,
    short* __restrict__ Wqkv, short* __restrict__ Wob,
    short* __restrict__ w1b, short* __restrict__ w2b,
    short* __restrict__ yb) {
  __shared__ float red[8];
  const int bi = blockIdx.x, tid = threadIdx.x;
  if (bi < 3072) {
    const float* src = bi < 1024 ? WQ : (bi < 2048 ? WK : WV);
    const float4 v = ((const float4*)(src + (size_t)(bi & 1023) * 1024))[tid];
    short4v o;
    o[0] = f2bf(v.x); o[1] = f2bf(v.y); o[2] = f2bf(v.z); o[3] = f2bf(v.w);
    ((short4v*)(Wqkv + (size_t)bi * 1024))[tid] = o;
  } else if (bi < 7168) {
    const int i = (bi - 3072) * 256 + tid;
    const float4 v = ((const float4*)w1)[i];
    short4v o;
    o[0] = f2bf(v.x); o[1] = f2bf(v.y); o[2] = f2bf(v.z); o[3] = f2bf(v.w);
    ((short4v*)w1b)[i] = o;
  } else if (bi < 11264) {
    const int i = (bi - 7168) * 256 + tid;
    const float4 v = ((const float4*)w2)[i];
    short4v o;
    o[0] = f2bf(v.x); o[1] = f2bf(v.y); o[2] = f2bf(v.z); o[3] = f2bf(v.w);
    ((short4v*)w2b)[i] = o;
  } else if (bi < 15360) {
    const int idx = (bi - 11264) * 256 + tid;  // [D][H*DH] out
    const int d = idx >> 10, cc = idx & 1023;
    const int i = cc >> 6, h = cc & 63;
    Wob[idx] = f2bf(WO[((size_t)d * 64 + h) * 16 + i]);
  } else {
    const int row = bi - 15360;
    const int lane = tid & 63, wave = tid >> 6;
    const float4 xv = *(const float4*)&x[(size_t)row * 1024 + tid * 4];
    float s1 = xv.x + xv.y + xv.z + xv.w;
    float s2 = xv.x * xv.x + xv.y * xv.y + xv.z * xv.z + xv.w * xv.w;
#pragma unroll
    for (int off = 1; off < 64; off <<= 1) {
      s1 += __shfl_xor(s1, off);
      s2 += __shfl_xor(s2, off);
    }
    if (lane == 0) { red[wave] = s1; red[4 + wave] = s2; }
    __syncthreads();
    s1 = red[0] + red[1] + red[2] + red[3];
    s2 = red[4] + red[5] + red[6] + red[7];
    const float mu = s1 * (1.0f / 1024.0f);
    const float var = s2 * (1.0f / 1024.0f) - mu * mu;
    const float rs = rsqrtf(var + 1e-5f);
    const float4 wv = *(const float4*)&lnw[tid * 4];
    const float4 bv = *(const float4*)&lnb[tid * 4];
    short4v o;
    o[0] = f2bf((xv.x - mu) * rs * wv.x + bv.x);
    o[1] = f2bf((xv.y - mu) * rs * wv.y + bv.y);
    o[2] = f2bf((xv.z - mu) * rs * wv.z + bv.z);
    o[3] = f2bf((xv.w - mu) * rs * wv.w + bv.w);
    *(short4v*)&yb[(size_t)row * 1024 + tid * 4] = o;
  }
}

// ---------------- LayerNorm standalone (LN2) ----------------
__global__ __launch_bounds__(256) void ln_kernel(const float* __restrict__ x,
                                                 const float* __restrict__ w,
                                                 const float* __restrict__ b,
                                                 short* __restrict__ y) {
  const int row = blockIdx.x, tid = threadIdx.x;
  const int lane = tid & 63, wave = tid >> 6;
  const float4 xv = *(const float4*)&x[(size_t)row * 1024 + tid * 4];
  float s1 = xv.x + xv.y + xv.z + xv.w;
  float s2 = xv.x * xv.x + xv.y * xv.y + xv.z * xv.z + xv.w * xv.w;
#pragma unroll
  for (int off = 1; off < 64; off <<= 1) {
    s1 += __shfl_xor(s1, off);
    s2 += __shfl_xor(s2, off);
  }
  __shared__ float red[8];
  if (lane == 0) { red[wave] = s1; red[4 + wave] = s2; }
  __syncthreads();
  s1 = red[0] + red[1] + red[2] + red[3];
  s2 = red[4] + red[5] + red[6] + red[7];
  const float mu = s1 * (1.0f / 1024.0f);
  const float var = s2 * (1.0f / 1024.0f) - mu * mu;
  const float rs = rsqrtf(var + 1e-5f);
  const float4 wv = *(const float4*)&w[tid * 4];
  const float4 bv = *(const float4*)&b[tid * 4];
  short4v o;
  o[0] = f2bf((xv.x - mu) * rs * wv.x + bv.x);
  o[1] = f2bf((xv.y - mu) * rs * wv.y + bv.y);
  o[2] = f2bf((xv.z - mu) * rs * wv.z + bv.z);
  o[3] = f2bf((xv.w - mu) * rs * wv.w + bv.w);
  *(short4v*)&y[(size_t)row * 1024 + tid * 4] = o;
}

// ------- GEMM: C = A*Bw^T, bf16, fp32 acc, tile BMxBN -----
// Shape-conditional config (R17/R18 measured):
//   Large-N GEMMs (QKV N=3072, MLP1 N=4096): 128x128 single-buffer.
//   N=1024 GEMMs (WO-proj, MLP2): 128x64 DBUF (48KB -> 3 blocks/CU).
template <int MODE, int BM, int BN, bool DBUF>
__global__ __launch_bounds__(256) void gemm_bf16k(
    const short* __restrict__ A, const short* __restrict__ Bw,
    float* __restrict__ outF, short* __restrict__ outB,
    const float* __restrict__ resid, const float* __restrict__ bias,
    int M, int N, int K) {
  constexpr int RBM = BM / 2, RBN = BN / 2;
  constexpr int FM = RBM / 16, FN = RBN / 16;
  constexpr int TCA = BM / 8, TCB = BN / 8, TC = TCA + TCB;
  constexpr int NB = DBUF ? 2 : 1;
  __shared__ short As[NB][BM * 64];
  __shared__ short Bs[NB][BN * 64];
  const int tid = threadIdx.x, lane = tid & 63, wave = tid >> 6;
  const int nbx = gridDim.x, nwg = nbx * gridDim.y;
  int lid = (int)blockIdx.y * nbx + (int)blockIdx.x;
  lid = (lid & 7) * (nwg >> 3) + (lid >> 3);   // xcd-chunked remap (nwg%8==0)
  const int m0 = (lid / nbx) * BM, n0 = (lid % nbx) * BN;
  const int wm = (wave & 1) * RBM, wn = (wave >> 1) * RBN;
  const int lr = lane >> 3;        // row within 8-row chunk
  const int lc = (lane & 7) * 8;   // elem col within chunk row
  f32x4 acc[FM][FN] = {};

  auto stage = [&](int d, int kt) {
#pragma unroll
    for (int i = 0; i < TC / 4; ++i) {
      const int ch = i * 4 + wave;
      if (ch < TCA) {
        GLOAD16(A + (size_t)(m0 + ch * 8 + lr) * K + kt + lc, &As[d][ch * 512]);
      } else {
        const int cb = ch - TCA;
        GLOAD16(Bw + (size_t)(n0 + cb * 8 + lr) * K + kt + lc, &Bs[d][cb * 512]);
      }
    }
  };
  auto compute = [&](int d) {
#pragma unroll
    for (int kk = 0; kk < 64; kk += 32) {
      bf16x8 af[FM], bfr[FN];
#pragma unroll
      for (int i2 = 0; i2 < FM; ++i2)
        af[i2] = *(const bf16x8*)&As[d][(wm + i2 * 16 + (lane & 15)) * 64 + kk + (lane >> 4) * 8];
#pragma unroll
      for (int j2 = 0; j2 < FN; ++j2)
        bfr[j2] = *(const bf16x8*)&Bs[d][(wn + j2 * 16 + (lane & 15)) * 64 + kk + (lane >> 4) * 8];
#pragma unroll
      for (int i2 = 0; i2 < FM; ++i2)
#pragma unroll
        for (int j2 = 0; j2 < FN; ++j2)
          acc[i2][j2] = mfma16(af[i2], bfr[j2], acc[i2][j2]);
    }
  };

  const int nt = K >> 6;
  if constexpr (DBUF) {
    stage(0, 0);
    __syncthreads();
    for (int t = 0; t < nt; ++t) {
      const int cur = t & 1;
      if (t + 1 < nt) stage(cur ^ 1, (t + 1) << 6);
      compute(cur);
      __syncthreads();
    }
  } else {
    for (int t = 0; t < nt; ++t) {
      stage(0, t << 6);
      __syncthreads();
      compute(0);
      __syncthreads();
    }
  }

#pragma unroll
  for (int i2 = 0; i2 < FM; ++i2)
#pragma unroll
    for (int j2 = 0; j2 < FN; ++j2)
#pragma unroll
      for (int r = 0; r < 4; ++r) {
        const int m = m0 + wm + i2 * 16 + (lane >> 4) * 4 + r;
        const int n = n0 + wn + j2 * 16 + (lane & 15);
        const float v = acc[i2][j2][r];
        if (MODE == 0) {
          const size_t oi = (size_t)(n >> 10) * 4194304 +
              ((size_t)((m >> 11) * 16 + ((n & 1023) >> 6)) * 2048 + (m & 2047)) * 64 +
              (n & 63);
          outB[oi] = f2bf(v);
        } else if (MODE == 1) {
          outF[(size_t)m * N + n] = resid[(size_t)m * N + n] + v;
        } else if (MODE == 2) {
          const float t2 = v + bias[n];
          outB[(size_t)m * N + n] = f2bf(t2 > 0.0f ? t2 : 0.0f);
        } else {
          outF[(size_t)m * N + n] = resid[(size_t)m * N + n] + v + bias[n];
        }
      }
}

// ---------------- V transpose: [BH][S][64] -> [BH][64][S] ----------------
__global__ __launch_bounds__(256) void transpose_v(const short* __restrict__ V,
                                                   short* __restrict__ Vt) {
  __shared__ short t[64][72];
  const int bi = blockIdx.y;
  const int p0 = blockIdx.x * 64;
  const short* Vh = V + (size_t)bi * 2048 * 64;
  short* Vth = Vt + (size_t)bi * 64 * 2048;
  const int tid = threadIdx.x;
  {
    const int pr = tid >> 2, h0 = (tid & 3) * 16;
    const bf16x8* src = (const bf16x8*)&Vh[(size_t)(p0 + pr) * 64 + h0];
    bf16x8 v0 = src[0], v1 = src[1];
#pragma unroll
    for (int j = 0; j < 8; ++j) { t[pr][h0 + j] = v0[j]; t[pr][h0 + 8 + j] = v1[j]; }
  }
  __syncthreads();
  {
    const int hr = tid >> 2, pq = (tid & 3) * 16;
    bf16x8 o0, o1;
#pragma unroll
    for (int j = 0; j < 8; ++j) { o0[j] = t[pq + j][hr]; o1[j] = t[pq + 8 + j][hr]; }
    *(bf16x8*)&Vth[(size_t)hr * 2048 + p0 + pq] = o0;
    *(bf16x8*)&Vth[(size_t)hr * 2048 + p0 + pq + 8] = o1;
  }
}

// ---- attn_flash v4 + T5 setprio + XCD-chunked head locality (R20: -34us) --
__global__ __launch_bounds__(256, 2) void attn_flash(
    const short* __restrict__ Q, const short* __restrict__ K,
    const short* __restrict__ Vt, float* __restrict__ ml,
    short* __restrict__ zb) {
  __shared__ __align__(16) char smem[34816];
  const int tid = threadIdx.x, lane = tid & 63, pc = tid >> 6;
  const int g = lane >> 4, c = lane & 15;
  int lid = (int)blockIdx.y * 64 + (int)blockIdx.x;   // [0, 2048)
  lid = (lid & 7) * 256 + (lid >> 3);                 // XCD chunk: 4 heads/XCD
  const int bi = lid >> 6;
  const int qt = 63 - (lid & 63);        // heavy q-tiles first within chunk
  const int b = bi >> 4, hd = bi & 15;
  const size_t hoff = (size_t)bi * 2048 * 64;
  const short* Qh = Q + hoff;
  const short* Kh = K + hoff;
  const short* Vth = Vt + hoff;
  short* zbh = zb + (size_t)b * 2048 * 1024 + hd * 64;

  const int qw = qt * 32;
  const int P = qw + 32;
  const int csz = ((P + 511) >> 9) << 7;   // ceil(P/4) rounded up to 128
  const int p_lo = pc * csz;
  const int p_hi = min(p_lo + csz, P);

  short* pbuf = (short*)smem + pc * 4224;  // 32 rows x pitch 132
  float* mlb  = (float*)(smem + 33792);
  float* zm   = (float*)smem;

  const bf16x8* qp0 = (const bf16x8*)&Qh[(size_t)(qw + c) * 64];
  const bf16x8* qp1 = (const bf16x8*)&Qh[(size_t)(qw + 16 + c) * 64];
  bf16x8 aq[2][2];
  aq[0][0] = qp0[g]; aq[0][1] = qp0[4 + g];
  aq[1][0] = qp1[g]; aq[1][1] = qp1[4 + g];

  float m4[2][4], l4[2][4];
  f32x4 zacc[2][4] = {};
#pragma unroll
  for (int rb = 0; rb < 2; ++rb)
#pragma unroll
    for (int r = 0; r < 4; ++r) { m4[rb][r] = -1e30f; l4[rb][r] = 0.0f; }

  for (int p0 = p_lo; p0 < p_hi; p0 += 128) {
    bf16x8 k0[8], k1[8];
#pragma unroll
    for (int kb = 0; kb < 8; ++kb) {
      int row = p0 + kb * 16 + c;
      row = row < 2047 ? row : 2047;   // clamp; masked below via p<=q
      const bf16x8* kp = (const bf16x8*)&Kh[(size_t)row * 64];
      k0[kb] = kp[g]; k1[kb] = kp[4 + g];
    }
    const bool needmask = (p0 + 128 > qw);   // wave-uniform
#pragma unroll
    for (int rb = 0; rb < 2; ++rb) {
      f32x4 s[8];
      __builtin_amdgcn_s_setprio(1);
#pragma unroll
      for (int kb = 0; kb < 8; ++kb) {
        f32x4 z4 = {0.0f, 0.0f, 0.0f, 0.0f};
        z4 = mfma16(aq[rb][0], k0[kb], z4);
        s[kb] = mfma16(aq[rb][1], k1[kb], z4);
      }
      __builtin_amdgcn_s_setprio(0);
#pragma unroll
      for (int r = 0; r < 4; ++r) {
        const int q = qw + rb * 16 + g * 4 + r;
        float v[8];
        if (needmask) {
#pragma unroll
          for (int kb = 0; kb < 8; ++kb)
            v[kb] = (p0 + kb * 16 + c <= q) ? s[kb][r] * 0.125f : -1e30f;
        } else {
#pragma unroll
          for (int kb = 0; kb < 8; ++kb) v[kb] = s[kb][r] * 0.125f;
        }
        float mx = fmaxf(fmaxf(fmaxf(v[0], v[1]), fmaxf(v[2], v[3])),
                         fmaxf(fmaxf(v[4], v[5]), fmaxf(v[6], v[7])));
#pragma unroll
        for (int off = 1; off < 16; off <<= 1)
          mx = fmaxf(mx, __shfl_xor(mx, off));   // row-uniform across c-lanes
        const float mn = fmaxf(m4[rb][r], mx);
        const float fac = __expf(m4[rb][r] - mn);
        m4[rb][r] = mn;
        float lsum = 0.0f;
        if (needmask) {
#pragma unroll
          for (int kb = 0; kb < 8; ++kb) {
            const int p = p0 + kb * 16 + c;
            const float e = (p <= q) ? __expf(v[kb] - mn) : 0.0f;
            lsum += e;
            pbuf[(rb * 16 + g * 4 + r) * 132 + kb * 16 + c] = f2bf(e);
          }
        } else {
#pragma unroll
          for (int kb = 0; kb < 8; ++kb) {
            const float e = __expf(v[kb] - mn);
            lsum += e;
            pbuf[(rb * 16 + g * 4 + r) * 132 + kb * 16 + c] = f2bf(e);
          }
        }
        l4[rb][r] = l4[rb][r] * fac + lsum;
#pragma unroll
        for (int hb = 0; hb < 4; ++hb) zacc[rb][hb][r] *= fac;
      }
    }
    // PV: pa from pbuf (two 8B reads, 8B-aligned at pitch 132), bv from Vt
    __builtin_amdgcn_s_setprio(1);
#pragma unroll
    for (int j = 0; j < 4; ++j) {
      const short4v p0lo = *(const short4v*)&pbuf[c * 132 + j * 32 + g * 8];
      const short4v p0hi = *(const short4v*)&pbuf[c * 132 + j * 32 + g * 8 + 4];
      const short4v p1lo = *(const short4v*)&pbuf[(16 + c) * 132 + j * 32 + g * 8];
      const short4v p1hi = *(const short4v*)&pbuf[(16 + c) * 132 + j * 32 + g * 8 + 4];
      const bf16x8 pa0 = __builtin_shufflevector(p0lo, p0hi, 0, 1, 2, 3, 4, 5, 6, 7);
      const bf16x8 pa1 = __builtin_shufflevector(p1lo, p1hi, 0, 1, 2, 3, 4, 5, 6, 7);
#pragma unroll
      for (int hb = 0; hb < 4; ++hb) {
        const bf16x8 bv =
            *(const bf16x8*)&Vth[(size_t)(hb * 16 + c) * 2048 + p0 + j * 32 + g * 8];
        zacc[0][hb] = mfma16(pa0, bv, zacc[0][hb]);
        zacc[1][hb] = mfma16(pa1, bv, zacc[1][hb]);
      }
    }
    __builtin_amdgcn_s_setprio(0);
  }

  // cross-lane l sum (m already row-uniform)
#pragma unroll
  for (int rb = 0; rb < 2; ++rb)
#pragma unroll
    for (int r = 0; r < 4; ++r)
#pragma unroll
      for (int off = 1; off < 16; off <<= 1)
        l4[rb][r] += __shfl_xor(l4[rb][r], off);

  if (c == 0) {
#pragma unroll
    for (int rb = 0; rb < 2; ++rb)
#pragma unroll
      for (int r = 0; r < 4; ++r) {
        mlb[(pc * 32 + rb * 16 + g * 4 + r) * 2 + 0] = m4[rb][r];
        mlb[(pc * 32 + rb * 16 + g * 4 + r) * 2 + 1] = l4[rb][r];
      }
  }
  __syncthreads();  // pbuf dead in all waves; mlb visible

  // phase C: m-aware flash combine of the 4 chunk partials
  if (pc != 0) {
#pragma unroll
    for (int rb = 0; rb < 2; ++rb)
#pragma unroll
      for (int hb = 0; hb < 4; ++hb)
#pragma unroll
        for (int r = 0; r < 4; ++r)
          zm[((pc - 1) * 32 + rb * 16 + g * 4 + r) * 68 + hb * 16 + c] = zacc[rb][hb][r];
  }
  __syncthreads();
  if (pc == 0) {
#pragma unroll
    for (int rb = 0; rb < 2; ++rb)
#pragma unroll
      for (int r = 0; r < 4; ++r) {
        const int row = rb * 16 + g * 4 + r;
        float M = -1e30f;
#pragma unroll
        for (int j = 0; j < 4; ++j) M = fmaxf(M, mlb[(j * 32 + row) * 2 + 0]);
        float w[4], L = 0.0f;
#pragma unroll
        for (int j = 0; j < 4; ++j) {
          w[j] = __expf(mlb[(j * 32 + row) * 2 + 0] - M);
          L += mlb[(j * 32 + row) * 2 + 1] * w[j];
        }
        const float iL = 1.0f / L;
#pragma unroll
        for (int hb = 0; hb < 4; ++hb) {
          float z = zacc[rb][hb][r] * w[0];
#pragma unroll
          for (int j = 1; j < 4; ++j)
            z += zm[((j - 1) * 32 + row) * 68 + hb * 16 + c] * w[j];
          zbh[(size_t)(qw + row) * 1024 + hb * 16 + c] = f2bf(z * iL);
        }
        if (c == 0)
          ((float2*)ml)[(size_t)bi * 2048 + qw + row] = make_float2(M, iL);
      }
  }
}

// ---- att_write + matched XCD head affinity (cross-kernel L2 reuse) ----
// Flat-grid remap so each XCD owns the SAME contiguous 4-head range that
// attn_flash just processed there -> K likely still L2-resident at dispatch.
__global__ __launch_bounds__(256) void att_write(
    const short* __restrict__ Q, const short* __restrict__ K,
    const float* __restrict__ ml, float* __restrict__ att) {
  __shared__ float fbuf_s[4][16 * 36];
  const int tid = threadIdx.x, lane = tid & 63, wave = tid >> 6;
  const int g = lane >> 4, c = lane & 15;
  int lid = (int)blockIdx.x;              // flat [0, 16384)
  lid = (lid & 7) * 2048 + (lid >> 3);    // XCD chunk: 4 heads/XCD (matched)
  const int bi = lid >> 9;
  const int rem = lid & 511;
  const int qt = rem & 63, pt = rem >> 6;
  const int qs = wave >> 1, ph = wave & 1;
  const int qw = qt * 32 + qs * 16;
  const int pb = pt * 256 + ph * 128;
  float* atth = att + (size_t)bi * 2048 * 2048;
  const int r0 = lane >> 3, c4 = (lane & 7) * 4;

  if (pb > qw + 15) {  // strip entirely above the diagonal: pure zeros
    const f32x4 zf = {0.0f, 0.0f, 0.0f, 0.0f};
#pragma unroll
    for (int j = 0; j < 4; ++j) {
      __builtin_nontemporal_store(zf, (f32x4*)&atth[(size_t)(qw + r0) * 2048 + pb + j * 32 + c4]);
      __builtin_nontemporal_store(zf, (f32x4*)&atth[(size_t)(qw + 8 + r0) * 2048 + pb + j * 32 + c4]);
    }
    return;
  }

  const size_t hoff = (size_t)bi * 2048 * 64;
  const short* Qh = Q + hoff;
  const short* Kh = K + hoff;
  const bf16x8* qp = (const bf16x8*)&Qh[(size_t)(qw + c) * 64];
  const bf16x8 aq0 = qp[g], aq1 = qp[4 + g];
  float m4[4], il[4];
#pragma unroll
  for (int r = 0; r < 4; ++r) {
    const float2 t = ((const float2*)ml)[(size_t)bi * 2048 + qw + g * 4 + r];
    m4[r] = t.x; il[r] = t.y;
  }
  float* fbuf = fbuf_s[wave];
  for (int p0 = pb; p0 < pb + 128; p0 += 32) {
    const bf16x8* kp0 = (const bf16x8*)&Kh[(size_t)(p0 + c) * 64];
    const bf16x8* kp1 = (const bf16x8*)&Kh[(size_t)(p0 + 16 + c) * 64];
    f32x4 s0 = {0.0f, 0.0f, 0.0f, 0.0f}, s1 = {0.0f, 0.0f, 0.0f, 0.0f};
    s0 = mfma16(aq0, kp0[g], s0);
    s0 = mfma16(aq1, kp0[4 + g], s0);
    s1 = mfma16(aq0, kp1[g], s1);
    s1 = mfma16(aq1, kp1[4 + g], s1);
#pragma unroll
    for (int f = 0; f < 2; ++f) {
      const f32x4& ss = f ? s1 : s0;
#pragma unroll
      for (int r = 0; r < 4; ++r) {
        const int q = qw + g * 4 + r, p = p0 + f * 16 + c;
        const float e = (p <= q) ? __expf(ss[r] * 0.125f - m4[r]) * il[r] : 0.0f;
        fbuf[(g * 4 + r) * 36 + f * 16 + c] = e;
      }
    }
    const f32x4 v0 = *(const f32x4*)&fbuf[r0 * 36 + c4];
    const f32x4 v1 = *(const f32x4*)&fbuf[(8 + r0) * 36 + c4];
    __builtin_nontemporal_store(v0, (f32x4*)&atth[(size_t)(qw + r0) * 2048 + p0 + c4]);
    __builtin_nontemporal_store(v1, (f32x4*)&atth[(size_t)(qw + 8 + r0) * 2048 + p0 + c4]);
  }
}

// ---------------- launch ----------------
extern "C" void kernel_launch(void* const* d_in, const int* in_sizes, int n_in,
                              void* d_out, int out_size, void* d_ws, size_t ws_size,
                              hipStream_t stream) {
  (void)in_sizes; (void)n_in; (void)out_size; (void)ws_size;
  const float* x    = (const float*)d_in[0];
  const float* WQ   = (const float*)d_in[1];
  const float* WK   = (const float*)d_in[2];
  const float* WV   = (const float*)d_in[3];
  const float* WO   = (const float*)d_in[4];
  const float* lnaw = (const float*)d_in[5];
  const float* lnab = (const float*)d_in[6];
  const float* lnmw = (const float*)d_in[7];
  const float* lnmb = (const float*)d_in[8];
  const float* w1   = (const float*)d_in[9];
  const float* b1   = (const float*)d_in[10];
  const float* w2   = (const float*)d_in[11];
  const float* b2   = (const float*)d_in[12];

  char* ws = (char*)d_ws;
  const size_t MB = 1024 * 1024;
  short* Wqkv = (short*)(ws + 0 * MB);   // 6MB: packed [3072][1024] bf16
  short* Wob  = (short*)(ws + 6 * MB);   // 2MB
  short* w1b  = (short*)(ws + 8 * MB);   // 8MB
  short* w2b  = (short*)(ws + 16 * MB);  // 8MB
  short* yb   = (short*)(ws + 24 * MB);  // 8MB (LN1 out; reused for LN2 out)
  short* Qb   = (short*)(ws + 32 * MB);  // 8MB  } contiguous: fused QKV
  short* Kb   = (short*)(ws + 40 * MB);  // 8MB  } scatter writes sel*4M
  short* Vb   = (short*)(ws + 48 * MB);  // 8MB  }
  short* Vtb  = (short*)(ws + 56 * MB);  // 8MB
  short* zbuf = (short*)(ws + 64 * MB);  // 8MB
  float* x1   = (float*)(ws + 72 * MB);  // 16MB (written after att_write reads mlw)
  float* mlw  = (float*)(ws + 72 * MB);  // 512KB, overlaps x1 (stream-ordered:
                                         // att_write consumes mlw BEFORE gemm1
                                         // writes x1)
  short* hb   = (short*)(ws + 32 * MB);  // 32MB, reuses Q/K/V/Vt (dead by MLP1)

  float* outx = (float*)d_out;
  float* att  = outx + (size_t)2 * 2048 * 1024;  // output 1 region

  // weight converts + LN1 in one dispatch
  prep_all<<<dim3(19456), dim3(256), 0, stream>>>(
      WQ, WK, WV, WO, w1, w2, x, lnaw, lnab, Wqkv, Wob, w1b, w2b, yb);

  // fused QKV projection: 128x128 single-buffer (best measured)
  gemm_bf16k<0, 128, 128, false><<<dim3(24, 32), dim3(256), 0, stream>>>(
      yb, Wqkv, nullptr, Qb, nullptr, nullptr, 4096, 3072, 1024);

  // V transpose for PV B-operand
  transpose_v<<<dim3(32, 32), dim3(256), 0, stream>>>(Vb, Vtb);

  // attention stats + z (online flash + setprio + XCD head-locality)
  attn_flash<<<dim3(64, 32), dim3(256), 0, stream>>>(Qb, Kb, Vtb, mlw, zbuf);

  // att materialization (matched XCD head affinity; store-BW-bound)
  att_write<<<dim3(16384), dim3(256), 0, stream>>>(Qb, Kb, mlw, att);

  // output projection + residual -> x1; 128x64 DBUF (thin-TLP shape)
  gemm_bf16k<1, 128, 64, true><<<dim3(16, 32), dim3(256), 0, stream>>>(
      zbuf, Wob, x1, nullptr, x, nullptr, 4096, 1024, 1024);

  // LN2
  ln_kernel<<<dim3(4096), dim3(256), 0, stream>>>(x1, lnmw, lnmb, yb);

  // MLP1: 128x128 single-buffer (best measured)
  gemm_bf16k<2, 128, 128, false><<<dim3(32, 32), dim3(256), 0, stream>>>(
      yb, w1b, nullptr, hb, nullptr, b1, 4096, 4096, 1024);
  // MLP2: 128x64 DBUF (thin-TLP shape)
  gemm_bf16k<3, 128, 64, true><<<dim3(16, 32), dim3(256), 0, stream>>>(
      hb, w2b, outx, nullptr, x1, b2, 4096, 1024, 4096);
}